// Round 2
// baseline (782.364 us; speedup 1.0000x reference)
//
#include <hip/hip_runtime.h>
#include <cmath>

#define BLK 256
#define SCAN_CHUNK 1024
#define BSHIFT 4  // 16 nodes per bucket; bucket region ~16*16*4B = 1KB in csr/pairs

// ---------------- CSR build ----------------

__global__ void count_kernel(const int* __restrict__ dst, int* __restrict__ cnt, int E) {
  int e = blockIdx.x * blockDim.x + threadIdx.x;
  if (e < E) atomicAdd(&cnt[dst[e]], 1);
}

__global__ void scan1_kernel(const int* __restrict__ cnt, int* __restrict__ partial,
                             int* __restrict__ blocksums, int n) {
  __shared__ int sdata[BLK];
  int t = threadIdx.x;
  int base = blockIdx.x * SCAN_CHUNK + t * 4;
  int v0 = (base + 0 < n) ? cnt[base + 0] : 0;
  int v1 = (base + 1 < n) ? cnt[base + 1] : 0;
  int v2 = (base + 2 < n) ? cnt[base + 2] : 0;
  int v3 = (base + 3 < n) ? cnt[base + 3] : 0;
  int s = v0 + v1 + v2 + v3;
  sdata[t] = s;
  __syncthreads();
  for (int off = 1; off < BLK; off <<= 1) {
    int x = (t >= off) ? sdata[t - off] : 0;
    __syncthreads();
    sdata[t] += x;
    __syncthreads();
  }
  int excl = sdata[t] - s;
  if (t == BLK - 1) blocksums[blockIdx.x] = sdata[t];
  int run = excl;
  if (base + 0 < n) partial[base + 0] = run; run += v0;
  if (base + 1 < n) partial[base + 1] = run; run += v1;
  if (base + 2 < n) partial[base + 2] = run; run += v2;
  if (base + 3 < n) partial[base + 3] = run;
}

__global__ void scan2_kernel(int* __restrict__ blocksums, int nb) {
  __shared__ int sdata[BLK];
  int t = threadIdx.x;
  int v = (t < nb) ? blocksums[t] : 0;
  sdata[t] = v;
  __syncthreads();
  for (int off = 1; off < BLK; off <<= 1) {
    int x = (t >= off) ? sdata[t - off] : 0;
    __syncthreads();
    sdata[t] += x;
    __syncthreads();
  }
  if (t < nb) blocksums[t] = sdata[t] - v;  // exclusive
}

// cursor may alias partial (read then write same index) — no restrict on cursor
__global__ void scan3_kernel(const int* partial, const int* __restrict__ blocksums,
                             int* __restrict__ row_start, int* cursor,
                             int n, int total) {
  int i = blockIdx.x * blockDim.x + threadIdx.x;
  if (i < n) {
    int r = partial[i] + blocksums[i / SCAN_CHUNK];
    row_start[i] = r;
    cursor[i] = r;
  }
  if (i == 0) row_start[n] = total;
}

// bucket write cursors: bcur[b] = row_start[min(b*16, n)] — bucket regions in pairs[]
// coincide exactly with final csr regions (row_start is the prefix over all nodes).
__global__ void bcur_init_kernel(const int* __restrict__ row_start, int* __restrict__ bcur,
                                 int nbuk, int n) {
  int b = blockIdx.x * blockDim.x + threadIdx.x;
  if (b < nbuk) {
    int node = b << BSHIFT;
    bcur[b] = row_start[node < n ? node : n];
  }
}

// Pass B: scatter (src,dst) into dst-bucket regions. 6250 concurrently-filling
// sequential write windows -> cache lines fill completely -> ~12.8MB dense writes
// instead of 1.6M x 64B write-allocate evictions.
__global__ void scatter_pairs_kernel(const int* __restrict__ src, const int* __restrict__ dst,
                                     int* __restrict__ bcur, int2* __restrict__ pairs, int E) {
  int e = blockIdx.x * blockDim.x + threadIdx.x;
  if (e < E) {
    int d = dst[e];
    int p = atomicAdd(&bcur[d >> BSHIFT], 1);
    pairs[p] = make_int2(src[e], d);
  }
}

// Pass C: stream pairs sequentially; final position is inside the SAME ~1KB bucket
// region being streamed -> csr writes and cursor atomics are L2-local and dense.
__global__ void scatter_final_kernel(const int2* __restrict__ pairs, int* __restrict__ cursor,
                                     int* __restrict__ csr, int E) {
  int e = blockIdx.x * blockDim.x + threadIdx.x;
  if (e < E) {
    int2 pr = pairs[e];
    int pos = atomicAdd(&cursor[pr.y], 1);
    csr[pos] = pr.x;
  }
}

// ---------------- FeaSt heads=4 ----------------

// xu[i,h] = sum_k x[i,k] * u[k,h]   (u is 16x4 row-major)
__global__ void xu4_kernel(const float* __restrict__ x, const float* __restrict__ u,
                           float* __restrict__ xu, int n) {
  __shared__ float su[64];
  if (threadIdx.x < 64) su[threadIdx.x] = u[threadIdx.x];
  __syncthreads();
  int i = blockIdx.x * blockDim.x + threadIdx.x;
  if (i >= n) return;
  const float4* xi = (const float4*)(x + i * 16);
  float a0 = 0.f, a1 = 0.f, a2 = 0.f, a3 = 0.f;
#pragma unroll
  for (int g = 0; g < 4; g++) {
    float4 v = xi[g];
    a0 += v.x * su[(g*4+0)*4+0] + v.y * su[(g*4+1)*4+0] + v.z * su[(g*4+2)*4+0] + v.w * su[(g*4+3)*4+0];
    a1 += v.x * su[(g*4+0)*4+1] + v.y * su[(g*4+1)*4+1] + v.z * su[(g*4+2)*4+1] + v.w * su[(g*4+3)*4+1];
    a2 += v.x * su[(g*4+0)*4+2] + v.y * su[(g*4+1)*4+2] + v.z * su[(g*4+2)*4+2] + v.w * su[(g*4+3)*4+2];
    a3 += v.x * su[(g*4+0)*4+3] + v.y * su[(g*4+1)*4+3] + v.z * su[(g*4+2)*4+3] + v.w * su[(g*4+3)*4+3];
  }
  *(float4*)(xu + i * 4) = make_float4(a0, a1, a2, a3);
}

// 4 threads per node. sub = tid&3 handles neighbors r0+sub, r0+sub+4, ...
// acc quad-reduced via shfl_xor; each sub-lane emits output float4 #sub.
// EPI: 0 = relu->out ; 1 = raw->out ; 2 = raw->out2 AND relu->out
template <int EPI>
__global__ void gather4_kernel(const float* __restrict__ x, const float* __restrict__ xu,
                               const int* __restrict__ row_start, const int* __restrict__ csr,
                               const float* __restrict__ W, const float* __restrict__ c,
                               const float* __restrict__ b,
                               float* __restrict__ out, float* __restrict__ out2, int n) {
  __shared__ float4 sW[256];  // W: 16 x 64 row-major; float4 idx = k*16 + h*4 + og
  __shared__ float sc[4];
  __shared__ float sb[16];
  {
    int t = threadIdx.x;
    for (int k = t; k < 1024; k += blockDim.x) ((float*)sW)[k] = W[k];
    if (t < 4) sc[t] = c[t];
    if (t < 16) sb[t] = b[t];
  }
  __syncthreads();
  int tid = blockIdx.x * blockDim.x + threadIdx.x;
  int i = tid >> 2;
  int sub = tid & 3;
  if (i >= n) return;

  float4 xui = *(const float4*)(xu + i * 4);
  float acc[4][16];
#pragma unroll
  for (int h = 0; h < 4; h++)
#pragma unroll
    for (int k = 0; k < 16; k++) acc[h][k] = 0.f;

  // self loop: logits = c  ->  q = softmax(c). Assigned to sub 3 (lightest tail).
  if (sub == 3) {
    float m = fmaxf(fmaxf(sc[0], sc[1]), fmaxf(sc[2], sc[3]));
    float e0 = __expf(sc[0] - m), e1 = __expf(sc[1] - m), e2 = __expf(sc[2] - m), e3 = __expf(sc[3] - m);
    float inv = 1.0f / (e0 + e1 + e2 + e3);
    float q[4] = {e0 * inv, e1 * inv, e2 * inv, e3 * inv};
    const float4* xi = (const float4*)(x + i * 16);
#pragma unroll
    for (int g = 0; g < 4; g++) {
      float4 v = xi[g];
#pragma unroll
      for (int h = 0; h < 4; h++) {
        acc[h][g * 4 + 0] += q[h] * v.x;
        acc[h][g * 4 + 1] += q[h] * v.y;
        acc[h][g * 4 + 2] += q[h] * v.z;
        acc[h][g * 4 + 3] += q[h] * v.w;
      }
    }
  }

  int r0 = row_start[i], r1 = row_start[i + 1];
  for (int r = r0 + sub; r < r1; r += 4) {
    int j = csr[r];
    float4 xuj = *(const float4*)(xu + j * 4);
    float l0 = xuj.x - xui.x + sc[0];
    float l1 = xuj.y - xui.y + sc[1];
    float l2 = xuj.z - xui.z + sc[2];
    float l3 = xuj.w - xui.w + sc[3];
    float m = fmaxf(fmaxf(l0, l1), fmaxf(l2, l3));
    float e0 = __expf(l0 - m), e1 = __expf(l1 - m), e2 = __expf(l2 - m), e3 = __expf(l3 - m);
    float inv = 1.0f / (e0 + e1 + e2 + e3);
    float q0 = e0 * inv, q1 = e1 * inv, q2 = e2 * inv, q3 = e3 * inv;
    const float4* xj = (const float4*)(x + j * 16);
#pragma unroll
    for (int g = 0; g < 4; g++) {
      float4 v = xj[g];
      acc[0][g * 4 + 0] += q0 * v.x; acc[0][g * 4 + 1] += q0 * v.y; acc[0][g * 4 + 2] += q0 * v.z; acc[0][g * 4 + 3] += q0 * v.w;
      acc[1][g * 4 + 0] += q1 * v.x; acc[1][g * 4 + 1] += q1 * v.y; acc[1][g * 4 + 2] += q1 * v.z; acc[1][g * 4 + 3] += q1 * v.w;
      acc[2][g * 4 + 0] += q2 * v.x; acc[2][g * 4 + 1] += q2 * v.y; acc[2][g * 4 + 2] += q2 * v.z; acc[2][g * 4 + 3] += q2 * v.w;
      acc[3][g * 4 + 0] += q3 * v.x; acc[3][g * 4 + 1] += q3 * v.y; acc[3][g * 4 + 2] += q3 * v.z; acc[3][g * 4 + 3] += q3 * v.w;
    }
  }

  // quad reduction (lanes {4m,4m+1,4m+2,4m+3} hold partials of node i)
#pragma unroll
  for (int h = 0; h < 4; h++)
#pragma unroll
    for (int k = 0; k < 16; k++) {
      float v = acc[h][k];
      v += __shfl_xor(v, 1);
      v += __shfl_xor(v, 2);
      acc[h][k] = v;
    }

  float invdeg = 1.0f / (float)(r1 - r0 + 1);
  // each sub-lane computes output float4 #sub
  {
    int og = sub;
    float s0 = 0.f, s1 = 0.f, s2 = 0.f, s3 = 0.f;
#pragma unroll
    for (int k = 0; k < 16; k++) {
#pragma unroll
      for (int h = 0; h < 4; h++) {
        float4 w = sW[k * 16 + h * 4 + og];
        float a = acc[h][k];
        s0 += a * w.x; s1 += a * w.y; s2 += a * w.z; s3 += a * w.w;
      }
    }
    float o0 = s0 * invdeg + sb[og * 4 + 0];
    float o1 = s1 * invdeg + sb[og * 4 + 1];
    float o2 = s2 * invdeg + sb[og * 4 + 2];
    float o3 = s3 * invdeg + sb[og * 4 + 3];
    if (EPI == 1) {
      *(float4*)(out + i * 16 + og * 4) = make_float4(o0, o1, o2, o3);
    } else if (EPI == 0) {
      *(float4*)(out + i * 16 + og * 4) =
          make_float4(fmaxf(o0, 0.f), fmaxf(o1, 0.f), fmaxf(o2, 0.f), fmaxf(o3, 0.f));
    } else {
      *(float4*)(out2 + i * 16 + og * 4) = make_float4(o0, o1, o2, o3);
      *(float4*)(out + i * 16 + og * 4) =
          make_float4(fmaxf(o0, 0.f), fmaxf(o1, 0.f), fmaxf(o2, 0.f), fmaxf(o3, 0.f));
    }
  }
}

// ---------------- FeaSt heads=1 (softmax over 1 head == 1: pure mean agg + matvec) ----------------
// 4 threads per node, same decomposition as gather4.

template <int RELU>
__global__ void gather1_kernel(const float* __restrict__ x, const int* __restrict__ row_start,
                               const int* __restrict__ csr, const float* __restrict__ W,
                               const float* __restrict__ b, float* __restrict__ out, int n) {
  __shared__ float4 sW[64];  // 16x16, float4 idx = k*4+og
  __shared__ float sb[16];
  {
    int t = threadIdx.x;
    for (int k = t; k < 256; k += blockDim.x) ((float*)sW)[k] = W[k];
    if (t < 16) sb[t] = b[t];
  }
  __syncthreads();
  int tid = blockIdx.x * blockDim.x + threadIdx.x;
  int i = tid >> 2;
  int sub = tid & 3;
  if (i >= n) return;

  float acc[16];
#pragma unroll
  for (int k = 0; k < 16; k++) acc[k] = 0.f;

  if (sub == 3) {  // self loop
    const float4* xi = (const float4*)(x + i * 16);
#pragma unroll
    for (int g = 0; g < 4; g++) {
      float4 v = xi[g];
      acc[g * 4 + 0] += v.x; acc[g * 4 + 1] += v.y; acc[g * 4 + 2] += v.z; acc[g * 4 + 3] += v.w;
    }
  }

  int r0 = row_start[i], r1 = row_start[i + 1];
  for (int r = r0 + sub; r < r1; r += 4) {
    int j = csr[r];
    const float4* xj = (const float4*)(x + j * 16);
#pragma unroll
    for (int g = 0; g < 4; g++) {
      float4 v = xj[g];
      acc[g * 4 + 0] += v.x; acc[g * 4 + 1] += v.y; acc[g * 4 + 2] += v.z; acc[g * 4 + 3] += v.w;
    }
  }

#pragma unroll
  for (int k = 0; k < 16; k++) {
    float v = acc[k];
    v += __shfl_xor(v, 1);
    v += __shfl_xor(v, 2);
    acc[k] = v;
  }

  float invdeg = 1.0f / (float)(r1 - r0 + 1);
  {
    int og = sub;
    float s0 = 0.f, s1 = 0.f, s2 = 0.f, s3 = 0.f;
#pragma unroll
    for (int k = 0; k < 16; k++) {
      float4 w = sW[k * 4 + og];
      float a = acc[k];
      s0 += a * w.x; s1 += a * w.y; s2 += a * w.z; s3 += a * w.w;
    }
    float o0 = s0 * invdeg + sb[og * 4 + 0];
    float o1 = s1 * invdeg + sb[og * 4 + 1];
    float o2 = s2 * invdeg + sb[og * 4 + 2];
    float o3 = s3 * invdeg + sb[og * 4 + 3];
    if (RELU) {
      o0 = fmaxf(o0, 0.f); o1 = fmaxf(o1, 0.f); o2 = fmaxf(o2, 0.f); o3 = fmaxf(o3, 0.f);
    }
    *(float4*)(out + i * 16 + og * 4) = make_float4(o0, o1, o2, o3);
  }
}

// ---------------- BatchNorm ----------------

__global__ void bn_stats_kernel(const float* __restrict__ x, float* __restrict__ stats, int n) {
  __shared__ float ss[32];
  int t = threadIdx.x;
  if (t < 32) ss[t] = 0.f;
  __syncthreads();
  float ls[16], lq[16];
#pragma unroll
  for (int k = 0; k < 16; k++) { ls[k] = 0.f; lq[k] = 0.f; }
  for (int i = blockIdx.x * blockDim.x + t; i < n; i += gridDim.x * blockDim.x) {
    const float4* xi = (const float4*)(x + i * 16);
#pragma unroll
    for (int g = 0; g < 4; g++) {
      float4 v = xi[g];
      ls[g * 4 + 0] += v.x; lq[g * 4 + 0] += v.x * v.x;
      ls[g * 4 + 1] += v.y; lq[g * 4 + 1] += v.y * v.y;
      ls[g * 4 + 2] += v.z; lq[g * 4 + 2] += v.z * v.z;
      ls[g * 4 + 3] += v.w; lq[g * 4 + 3] += v.w * v.w;
    }
  }
#pragma unroll
  for (int k = 0; k < 16; k++) {
    atomicAdd(&ss[k], ls[k]);
    atomicAdd(&ss[16 + k], lq[k]);
  }
  __syncthreads();
  if (t < 32) atomicAdd(&stats[t], ss[t]);
}

// RESID: out = relu(bn(x)) (+ r1 + r2 if RESID)
template <int RESID>
__global__ void bn_apply_kernel(const float* __restrict__ x, const float* __restrict__ stats,
                                const float* __restrict__ g, const float* __restrict__ be,
                                const float* __restrict__ r1, const float* __restrict__ r2,
                                float* __restrict__ out, int n) {
  __shared__ float sscale[16], sshift[16];
  int t = threadIdx.x;
  if (t < 16) {
    float invn = 1.0f / (float)n;
    float mu = stats[t] * invn;
    float var = stats[16 + t] * invn - mu * mu;
    float sc = g[t] * rsqrtf(var + 1e-5f);
    sscale[t] = sc;
    sshift[t] = be[t] - mu * sc;
  }
  __syncthreads();
  int i = blockIdx.x * blockDim.x + t;
  if (i >= n) return;
#pragma unroll
  for (int og = 0; og < 4; og++) {
    float4 v = *(const float4*)(x + i * 16 + og * 4);
    float o0 = fmaxf(v.x * sscale[og * 4 + 0] + sshift[og * 4 + 0], 0.f);
    float o1 = fmaxf(v.y * sscale[og * 4 + 1] + sshift[og * 4 + 1], 0.f);
    float o2 = fmaxf(v.z * sscale[og * 4 + 2] + sshift[og * 4 + 2], 0.f);
    float o3 = fmaxf(v.w * sscale[og * 4 + 3] + sshift[og * 4 + 3], 0.f);
    if (RESID) {
      float4 a = *(const float4*)(r1 + i * 16 + og * 4);
      float4 bb = *(const float4*)(r2 + i * 16 + og * 4);
      o0 += a.x + bb.x; o1 += a.y + bb.y; o2 += a.z + bb.z; o3 += a.w + bb.w;
    }
    *(float4*)(out + i * 16 + og * 4) = make_float4(o0, o1, o2, o3);
  }
}

// ---------------- MLP head: 16 ->64 relu ->64 relu ->16 relu ->1 sigmoid ----------------

__global__ void mlp_kernel(const float* __restrict__ h,
                           const float* __restrict__ lw1, const float* __restrict__ lb1,
                           const float* __restrict__ lw2, const float* __restrict__ lb2,
                           const float* __restrict__ lw3, const float* __restrict__ lb3,
                           const float* __restrict__ ow, const float* __restrict__ ob,
                           float* __restrict__ out, int n) {
  __shared__ float4 s1[256];   // 16x64
  __shared__ float4 s2[1024];  // 64x64
  __shared__ float4 s3[256];   // 64x16
  __shared__ float sb1[64], sb2[64], sb3[16], sow[16], sob[1];
  {
    int t = threadIdx.x;
    for (int k = t; k < 1024; k += blockDim.x) ((float*)s1)[k] = lw1[k];
    for (int k = t; k < 4096; k += blockDim.x) ((float*)s2)[k] = lw2[k];
    for (int k = t; k < 1024; k += blockDim.x) ((float*)s3)[k] = lw3[k];
    if (t < 64) sb1[t] = lb1[t];
    if (t < 64) sb2[t] = lb2[t];
    if (t < 16) sb3[t] = lb3[t];
    if (t < 16) sow[t] = ow[t];
    if (t == 0) sob[0] = ob[0];
  }
  __syncthreads();
  int i = blockIdx.x * blockDim.x + threadIdx.x;
  if (i >= n) return;

  float in16[16];
  const float4* hp = (const float4*)(h + i * 16);
#pragma unroll
  for (int g = 0; g < 4; g++) {
    float4 v = hp[g];
    in16[g * 4 + 0] = v.x; in16[g * 4 + 1] = v.y; in16[g * 4 + 2] = v.z; in16[g * 4 + 3] = v.w;
  }

  float a[64];
#pragma unroll
  for (int og = 0; og < 16; og++) {
    float s0 = sb1[og * 4 + 0], sy = sb1[og * 4 + 1], sz = sb1[og * 4 + 2], sw = sb1[og * 4 + 3];
#pragma unroll
    for (int k = 0; k < 16; k++) {
      float4 w = s1[k * 16 + og];
      float v = in16[k];
      s0 += v * w.x; sy += v * w.y; sz += v * w.z; sw += v * w.w;
    }
    a[og * 4 + 0] = fmaxf(s0, 0.f); a[og * 4 + 1] = fmaxf(sy, 0.f);
    a[og * 4 + 2] = fmaxf(sz, 0.f); a[og * 4 + 3] = fmaxf(sw, 0.f);
  }

  float b2[64];
#pragma unroll
  for (int og = 0; og < 16; og++) {
    float s0 = sb2[og * 4 + 0], sy = sb2[og * 4 + 1], sz = sb2[og * 4 + 2], sw = sb2[og * 4 + 3];
#pragma unroll
    for (int k = 0; k < 64; k++) {
      float4 w = s2[k * 16 + og];
      float v = a[k];
      s0 += v * w.x; sy += v * w.y; sz += v * w.z; sw += v * w.w;
    }
    b2[og * 4 + 0] = fmaxf(s0, 0.f); b2[og * 4 + 1] = fmaxf(sy, 0.f);
    b2[og * 4 + 2] = fmaxf(sz, 0.f); b2[og * 4 + 3] = fmaxf(sw, 0.f);
  }

  float c3[16];
#pragma unroll
  for (int og = 0; og < 4; og++) {
    float s0 = sb3[og * 4 + 0], sy = sb3[og * 4 + 1], sz = sb3[og * 4 + 2], sw = sb3[og * 4 + 3];
#pragma unroll
    for (int k = 0; k < 64; k++) {
      float4 w = s3[k * 4 + og];
      float v = b2[k];
      s0 += v * w.x; sy += v * w.y; sz += v * w.z; sw += v * w.w;
    }
    c3[og * 4 + 0] = fmaxf(s0, 0.f); c3[og * 4 + 1] = fmaxf(sy, 0.f);
    c3[og * 4 + 2] = fmaxf(sz, 0.f); c3[og * 4 + 3] = fmaxf(sw, 0.f);
  }

  float z = sob[0];
#pragma unroll
  for (int k = 0; k < 16; k++) z += c3[k] * sow[k];
  out[i] = 1.0f / (1.0f + __expf(-z));
}

// ---------------- launch ----------------

extern "C" void kernel_launch(void* const* d_in, const int* in_sizes, int n_in,
                              void* d_out, int out_size, void* d_ws, size_t ws_size,
                              hipStream_t stream) {
  const float* x = (const float*)d_in[0];
  const int* ei = (const int*)d_in[1];
  const int N = in_sizes[0] / 16;
  const int E = in_sizes[1] / 2;
  const int* srcp = ei;
  const int* dstp = ei + E;

  const float* W1 = (const float*)d_in[2];  const float* u1 = (const float*)d_in[3];
  const float* c1 = (const float*)d_in[4];  const float* b1 = (const float*)d_in[5];
  const float* W2 = (const float*)d_in[6];  const float* u2 = (const float*)d_in[7];
  const float* c2 = (const float*)d_in[8];  const float* b2 = (const float*)d_in[9];
  const float* W3 = (const float*)d_in[10]; const float* u3 = (const float*)d_in[11];
  const float* c3 = (const float*)d_in[12]; const float* b3 = (const float*)d_in[13];
  const float* W4 = (const float*)d_in[14]; const float* b4 = (const float*)d_in[17];
  const float* W5 = (const float*)d_in[18]; const float* b5 = (const float*)d_in[21];
  const float* W6 = (const float*)d_in[22]; const float* b6 = (const float*)d_in[25];
  const float* g1 = (const float*)d_in[26]; const float* be1 = (const float*)d_in[27];
  const float* g2 = (const float*)d_in[28]; const float* be2 = (const float*)d_in[29];
  const float* lw1 = (const float*)d_in[30]; const float* lb1 = (const float*)d_in[31];
  const float* lw2 = (const float*)d_in[32]; const float* lb2 = (const float*)d_in[33];
  const float* lw3 = (const float*)d_in[34]; const float* lb3 = (const float*)d_in[35];
  const float* ow = (const float*)d_in[36]; const float* ob = (const float*)d_in[37];
  float* out = (float*)d_out;

  char* ws = (char*)d_ws;
  size_t off = 0;
  auto alloc = [&](size_t bytes) -> void* {
    void* p = ws + off;
    off = (off + bytes + 255) & ~(size_t)255;
    return p;
  };
  int* row_start = (int*)alloc((size_t)(N + 1) * 4);
  int* cnt = (int*)alloc((size_t)N * 4);
  int* partial = (int*)alloc((size_t)N * 4);  // also reused as final-scatter cursor
  int* blocksums = (int*)alloc(512 * 4);
  int* csr = (int*)alloc((size_t)E * 4);
  float* xu = (float*)alloc((size_t)N * 4 * 4);
  float* bufA = (float*)alloc((size_t)N * 16 * 4);
  float* bufB = (float*)alloc((size_t)N * 16 * 4);
  float* h2b = (float*)alloc((size_t)N * 16 * 4);
  float* h4b = (float*)alloc((size_t)N * 16 * 4);
  float* tmp = (float*)alloc((size_t)N * 16 * 4);
  float* stats = (float*)alloc(32 * 4);
  const int NBUK = (N + (1 << BSHIFT) - 1) >> BSHIFT;
  int* bcur = (int*)alloc((size_t)NBUK * 4);
  // pairs staging (E * 8B = 12.8MB) aliases bufA+bufB, which are contiguous
  // (N*16*4 = 6.4MB each, 256B-aligned with no gap) and unused until layer 1.
  int2* pairs = (int2*)bufA;

  const int NB = (N + BLK - 1) / BLK;       // node-parallel grid (1 thread/node)
  const int NG = (4 * N + BLK - 1) / BLK;   // gather grid (4 threads/node)
  const int EB = (E + BLK - 1) / BLK;       // edge-parallel grid
  const int nchunk = (N + SCAN_CHUNK - 1) / SCAN_CHUNK;
  const int BB = (NBUK + BLK - 1) / BLK;

  // ---- CSR build (per call; ws is re-poisoned every launch) ----
  hipMemsetAsync(cnt, 0, (size_t)N * 4, stream);
  count_kernel<<<EB, BLK, 0, stream>>>(dstp, cnt, E);
  scan1_kernel<<<nchunk, BLK, 0, stream>>>(cnt, partial, blocksums, N);
  scan2_kernel<<<1, BLK, 0, stream>>>(blocksums, nchunk);
  scan3_kernel<<<NB, BLK, 0, stream>>>(partial, blocksums, row_start, partial, N, E);
  bcur_init_kernel<<<BB, BLK, 0, stream>>>(row_start, bcur, NBUK, N);
  scatter_pairs_kernel<<<EB, BLK, 0, stream>>>(srcp, dstp, bcur, pairs, E);
  scatter_final_kernel<<<EB, BLK, 0, stream>>>(pairs, partial, csr, E);

  // ---- Layer 1: h = relu(feast4(x)) -> bufA ----
  xu4_kernel<<<NB, BLK, 0, stream>>>(x, u1, xu, N);
  gather4_kernel<0><<<NG, BLK, 0, stream>>>(x, xu, row_start, csr, W1, c1, b1, bufA, nullptr, N);

  // ---- Layer 2: h2 = feast4(bufA) (raw -> h2b), relu -> bufB ----
  xu4_kernel<<<NB, BLK, 0, stream>>>(bufA, u2, xu, N);
  gather4_kernel<2><<<NG, BLK, 0, stream>>>(bufA, xu, row_start, csr, W2, c2, b2, bufB, h2b, N);

  // ---- Layer 3: h3 = relu(bn(feast4(bufB))) -> bufA ----
  xu4_kernel<<<NB, BLK, 0, stream>>>(bufB, u3, xu, N);
  gather4_kernel<1><<<NG, BLK, 0, stream>>>(bufB, xu, row_start, csr, W3, c3, b3, tmp, nullptr, N);
  hipMemsetAsync(stats, 0, 32 * 4, stream);
  bn_stats_kernel<<<256, BLK, 0, stream>>>(tmp, stats, N);
  bn_apply_kernel<0><<<NB, BLK, 0, stream>>>(tmp, stats, g1, be1, nullptr, nullptr, bufA, N);

  // ---- Layer 4: h4 = relu(feast1(bufA)) -> h4b ----
  gather1_kernel<1><<<NG, BLK, 0, stream>>>(bufA, row_start, csr, W4, b4, h4b, N);

  // ---- Layer 5: h5 = relu(feast1(h4b)) -> bufB ----
  gather1_kernel<1><<<NG, BLK, 0, stream>>>(h4b, row_start, csr, W5, b5, bufB, N);

  // ---- Layer 6: h6 = relu(bn(feast1(bufB))) + h2b + h4b -> bufA ----
  gather1_kernel<0><<<NG, BLK, 0, stream>>>(bufB, row_start, csr, W6, b6, tmp, N);
  hipMemsetAsync(stats, 0, 32 * 4, stream);
  bn_stats_kernel<<<256, BLK, 0, stream>>>(tmp, stats, N);
  bn_apply_kernel<1><<<NB, BLK, 0, stream>>>(tmp, stats, g2, be2, h2b, h4b, bufA, N);

  // ---- MLP head -> out ----
  mlp_kernel<<<NB, BLK, 0, stream>>>(bufA, lw1, lb1, lw2, lb2, lw3, lb3, ow, ob, out, N);
}

// Round 3
// 689.133 us; speedup vs baseline: 1.1353x; 1.1353x over previous
//
#include <hip/hip_runtime.h>
#include <cmath>

#define BLK 256
#define BSHIFT 9          // 512 nodes per bucket; ~8K edges (~65KB pairs) per bucket
#define EPT 16            // edges per thread in binning kernels
#define TILE (BLK * EPT)  // 4096 edges per tile

// ---------------- CSR build: LDS-binned bucket scatter ----------------

// Pass 0: per-tile LDS histogram of dst buckets -> global bucket counts.
__global__ void bhist_kernel(const int* __restrict__ dst, int* __restrict__ bcnt,
                             int E, int nbuk) {
  __shared__ int hist[256];
  int t = threadIdx.x;
  hist[t] = 0;
  __syncthreads();
  int base = blockIdx.x * TILE;
#pragma unroll
  for (int k = 0; k < EPT; k++) {
    int e = base + k * BLK + t;
    if (e < E) atomicAdd(&hist[dst[e] >> BSHIFT], 1);
  }
  __syncthreads();
  if (t < nbuk && hist[t] > 0) atomicAdd(&bcnt[t], hist[t]);
}

// 1-block exclusive scan over bucket counts -> gbase (bases) and gbcur (cursors).
__global__ void bscan_kernel(const int* __restrict__ bcnt, int* __restrict__ gbase,
                             int* __restrict__ gbcur, int nbuk, int E) {
  __shared__ int sdata[BLK];
  int t = threadIdx.x;
  int v = (t < nbuk) ? bcnt[t] : 0;
  sdata[t] = v;
  __syncthreads();
  for (int off = 1; off < BLK; off <<= 1) {
    int x = (t >= off) ? sdata[t - off] : 0;
    __syncthreads();
    sdata[t] += x;
    __syncthreads();
  }
  int excl = sdata[t] - v;
  if (t < nbuk) { gbase[t] = excl; gbcur[t] = excl; }
  if (t == 0) gbase[nbuk] = E;
}

// Pass 1: LDS-binned scatter. Each tile reserves ONE contiguous chunk per bucket
// (single global atomicAdd) and writes each bucket's edges as a contiguous burst
// (~21 edges = 168B avg). Full cache lines are produced by a single wave burst —
// write coalescing no longer depends on L2 retention (round-2 failure mode:
// streaming reads evicted partially-filled write lines -> 91MB writebacks).
__global__ void scatter_pairs_lds_kernel(const int* __restrict__ src, const int* __restrict__ dst,
                                         int* __restrict__ gbcur, int2* __restrict__ pairs,
                                         int E, int nbuk) {
  __shared__ int hist[256];
  __shared__ int chunk[256];
  int t = threadIdx.x;
  hist[t] = 0;
  __syncthreads();
  int base = blockIdx.x * TILE;
  int es[EPT], ed[EPT];
#pragma unroll
  for (int k = 0; k < EPT; k++) {
    int e = base + k * BLK + t;
    if (e < E) {
      es[k] = src[e];
      ed[k] = dst[e];
      atomicAdd(&hist[ed[k] >> BSHIFT], 1);
    } else {
      ed[k] = -1;
    }
  }
  __syncthreads();
  if (t < nbuk && hist[t] > 0) chunk[t] = atomicAdd(&gbcur[t], hist[t]);
  __syncthreads();
#pragma unroll
  for (int k = 0; k < EPT; k++) {
    if (ed[k] >= 0) {
      int p = atomicAdd(&chunk[ed[k] >> BSHIFT], 1);
      pairs[p] = make_int2(es[k], ed[k]);
    }
  }
}

// Pass 2: one block per bucket. Per-node counts + exclusive scan entirely in LDS,
// writes row_start slice, then scatters csr within its own ~32KB region
// (single block -> single XCD -> L2-local; all cursor atomics in LDS).
// Replaces count_kernel + scan1/2/3 + scatter_final.
__global__ void bucket_build_kernel(const int2* __restrict__ pairs, const int* __restrict__ gbase,
                                    int* __restrict__ row_start, int* __restrict__ csr,
                                    int n, int nbuk, int E) {
  __shared__ int cnt[512];
  __shared__ int excl[512];
  __shared__ int s2[BLK];
  int b = blockIdx.x;
  int t = threadIdx.x;
  int n0 = b << BSHIFT;
  int n1 = min(n0 + (1 << BSHIFT), n);
  int bb0 = gbase[b], bb1 = gbase[b + 1];
  cnt[t] = 0; cnt[t + 256] = 0;
  __syncthreads();
  for (int r = bb0 + t; r < bb1; r += BLK) atomicAdd(&cnt[pairs[r].y - n0], 1);
  __syncthreads();
  // pairwise sums then 256-wide scan
  s2[t] = cnt[2 * t] + cnt[2 * t + 1];
  __syncthreads();
  int v = s2[t];
  for (int off = 1; off < BLK; off <<= 1) {
    int x = (t >= off) ? s2[t - off] : 0;
    __syncthreads();
    s2[t] += x;
    __syncthreads();
  }
  int e2 = s2[t] - v;  // exclusive over pair-sums
  excl[2 * t] = e2;
  excl[2 * t + 1] = e2 + cnt[2 * t];
  __syncthreads();
  // row_start for this bucket's nodes
  for (int k = t; k < n1 - n0; k += BLK) row_start[n0 + k] = bb0 + excl[k];
  if (b == nbuk - 1 && t == 0) row_start[n] = E;
  // reuse cnt[] as global-position cursors
  cnt[2 * t] = bb0 + excl[2 * t];
  cnt[2 * t + 1] = bb0 + excl[2 * t + 1];
  __syncthreads();
  for (int r = bb0 + t; r < bb1; r += BLK) {
    int2 pr = pairs[r];
    int pos = atomicAdd(&cnt[pr.y - n0], 1);
    csr[pos] = pr.x;
  }
}

// ---------------- FeaSt heads=4 ----------------

// xu[i,h] = sum_k x[i,k] * u[k,h]   (u is 16x4 row-major)
__global__ void xu4_kernel(const float* __restrict__ x, const float* __restrict__ u,
                           float* __restrict__ xu, int n) {
  __shared__ float su[64];
  if (threadIdx.x < 64) su[threadIdx.x] = u[threadIdx.x];
  __syncthreads();
  int i = blockIdx.x * blockDim.x + threadIdx.x;
  if (i >= n) return;
  const float4* xi = (const float4*)(x + i * 16);
  float a0 = 0.f, a1 = 0.f, a2 = 0.f, a3 = 0.f;
#pragma unroll
  for (int g = 0; g < 4; g++) {
    float4 v = xi[g];
    a0 += v.x * su[(g*4+0)*4+0] + v.y * su[(g*4+1)*4+0] + v.z * su[(g*4+2)*4+0] + v.w * su[(g*4+3)*4+0];
    a1 += v.x * su[(g*4+0)*4+1] + v.y * su[(g*4+1)*4+1] + v.z * su[(g*4+2)*4+1] + v.w * su[(g*4+3)*4+1];
    a2 += v.x * su[(g*4+0)*4+2] + v.y * su[(g*4+1)*4+2] + v.z * su[(g*4+2)*4+2] + v.w * su[(g*4+3)*4+2];
    a3 += v.x * su[(g*4+0)*4+3] + v.y * su[(g*4+1)*4+3] + v.z * su[(g*4+2)*4+3] + v.w * su[(g*4+3)*4+3];
  }
  *(float4*)(xu + i * 4) = make_float4(a0, a1, a2, a3);
}

// 4 threads per node. sub = tid&3 handles neighbors r0+sub, r0+sub+4, ...
// acc quad-reduced via shfl_xor; each sub-lane emits output float4 #sub.
// EPI: 0 = relu->out ; 1 = raw->out ; 2 = raw->out2 AND relu->out
template <int EPI>
__global__ void gather4_kernel(const float* __restrict__ x, const float* __restrict__ xu,
                               const int* __restrict__ row_start, const int* __restrict__ csr,
                               const float* __restrict__ W, const float* __restrict__ c,
                               const float* __restrict__ b,
                               float* __restrict__ out, float* __restrict__ out2, int n) {
  __shared__ float4 sW[256];  // W: 16 x 64 row-major; float4 idx = k*16 + h*4 + og
  __shared__ float sc[4];
  __shared__ float sb[16];
  {
    int t = threadIdx.x;
    for (int k = t; k < 1024; k += blockDim.x) ((float*)sW)[k] = W[k];
    if (t < 4) sc[t] = c[t];
    if (t < 16) sb[t] = b[t];
  }
  __syncthreads();
  int tid = blockIdx.x * blockDim.x + threadIdx.x;
  int i = tid >> 2;
  int sub = tid & 3;
  if (i >= n) return;

  float4 xui = *(const float4*)(xu + i * 4);
  float acc[4][16];
#pragma unroll
  for (int h = 0; h < 4; h++)
#pragma unroll
    for (int k = 0; k < 16; k++) acc[h][k] = 0.f;

  // self loop: logits = c  ->  q = softmax(c). Assigned to sub 3 (lightest tail).
  if (sub == 3) {
    float m = fmaxf(fmaxf(sc[0], sc[1]), fmaxf(sc[2], sc[3]));
    float e0 = __expf(sc[0] - m), e1 = __expf(sc[1] - m), e2 = __expf(sc[2] - m), e3 = __expf(sc[3] - m);
    float inv = 1.0f / (e0 + e1 + e2 + e3);
    float q[4] = {e0 * inv, e1 * inv, e2 * inv, e3 * inv};
    const float4* xi = (const float4*)(x + i * 16);
#pragma unroll
    for (int g = 0; g < 4; g++) {
      float4 v = xi[g];
#pragma unroll
      for (int h = 0; h < 4; h++) {
        acc[h][g * 4 + 0] += q[h] * v.x;
        acc[h][g * 4 + 1] += q[h] * v.y;
        acc[h][g * 4 + 2] += q[h] * v.z;
        acc[h][g * 4 + 3] += q[h] * v.w;
      }
    }
  }

  int r0 = row_start[i], r1 = row_start[i + 1];
  for (int r = r0 + sub; r < r1; r += 4) {
    int j = csr[r];
    float4 xuj = *(const float4*)(xu + j * 4);
    float l0 = xuj.x - xui.x + sc[0];
    float l1 = xuj.y - xui.y + sc[1];
    float l2 = xuj.z - xui.z + sc[2];
    float l3 = xuj.w - xui.w + sc[3];
    float m = fmaxf(fmaxf(l0, l1), fmaxf(l2, l3));
    float e0 = __expf(l0 - m), e1 = __expf(l1 - m), e2 = __expf(l2 - m), e3 = __expf(l3 - m);
    float inv = 1.0f / (e0 + e1 + e2 + e3);
    float q0 = e0 * inv, q1 = e1 * inv, q2 = e2 * inv, q3 = e3 * inv;
    const float4* xj = (const float4*)(x + j * 16);
#pragma unroll
    for (int g = 0; g < 4; g++) {
      float4 v = xj[g];
      acc[0][g * 4 + 0] += q0 * v.x; acc[0][g * 4 + 1] += q0 * v.y; acc[0][g * 4 + 2] += q0 * v.z; acc[0][g * 4 + 3] += q0 * v.w;
      acc[1][g * 4 + 0] += q1 * v.x; acc[1][g * 4 + 1] += q1 * v.y; acc[1][g * 4 + 2] += q1 * v.z; acc[1][g * 4 + 3] += q1 * v.w;
      acc[2][g * 4 + 0] += q2 * v.x; acc[2][g * 4 + 1] += q2 * v.y; acc[2][g * 4 + 2] += q2 * v.z; acc[2][g * 4 + 3] += q2 * v.w;
      acc[3][g * 4 + 0] += q3 * v.x; acc[3][g * 4 + 1] += q3 * v.y; acc[3][g * 4 + 2] += q3 * v.z; acc[3][g * 4 + 3] += q3 * v.w;
    }
  }

  // quad reduction (lanes {4m,4m+1,4m+2,4m+3} hold partials of node i)
#pragma unroll
  for (int h = 0; h < 4; h++)
#pragma unroll
    for (int k = 0; k < 16; k++) {
      float v = acc[h][k];
      v += __shfl_xor(v, 1);
      v += __shfl_xor(v, 2);
      acc[h][k] = v;
    }

  float invdeg = 1.0f / (float)(r1 - r0 + 1);
  // each sub-lane computes output float4 #sub
  {
    int og = sub;
    float s0 = 0.f, s1 = 0.f, s2 = 0.f, s3 = 0.f;
#pragma unroll
    for (int k = 0; k < 16; k++) {
#pragma unroll
      for (int h = 0; h < 4; h++) {
        float4 w = sW[k * 16 + h * 4 + og];
        float a = acc[h][k];
        s0 += a * w.x; s1 += a * w.y; s2 += a * w.z; s3 += a * w.w;
      }
    }
    float o0 = s0 * invdeg + sb[og * 4 + 0];
    float o1 = s1 * invdeg + sb[og * 4 + 1];
    float o2 = s2 * invdeg + sb[og * 4 + 2];
    float o3 = s3 * invdeg + sb[og * 4 + 3];
    if (EPI == 1) {
      *(float4*)(out + i * 16 + og * 4) = make_float4(o0, o1, o2, o3);
    } else if (EPI == 0) {
      *(float4*)(out + i * 16 + og * 4) =
          make_float4(fmaxf(o0, 0.f), fmaxf(o1, 0.f), fmaxf(o2, 0.f), fmaxf(o3, 0.f));
    } else {
      *(float4*)(out2 + i * 16 + og * 4) = make_float4(o0, o1, o2, o3);
      *(float4*)(out + i * 16 + og * 4) =
          make_float4(fmaxf(o0, 0.f), fmaxf(o1, 0.f), fmaxf(o2, 0.f), fmaxf(o3, 0.f));
    }
  }
}

// ---------------- FeaSt heads=1 (softmax over 1 head == 1: pure mean agg + matvec) ----------------
// 4 threads per node, same decomposition as gather4.

template <int RELU>
__global__ void gather1_kernel(const float* __restrict__ x, const int* __restrict__ row_start,
                               const int* __restrict__ csr, const float* __restrict__ W,
                               const float* __restrict__ b, float* __restrict__ out, int n) {
  __shared__ float4 sW[64];  // 16x16, float4 idx = k*4+og
  __shared__ float sb[16];
  {
    int t = threadIdx.x;
    for (int k = t; k < 256; k += blockDim.x) ((float*)sW)[k] = W[k];
    if (t < 16) sb[t] = b[t];
  }
  __syncthreads();
  int tid = blockIdx.x * blockDim.x + threadIdx.x;
  int i = tid >> 2;
  int sub = tid & 3;
  if (i >= n) return;

  float acc[16];
#pragma unroll
  for (int k = 0; k < 16; k++) acc[k] = 0.f;

  if (sub == 3) {  // self loop
    const float4* xi = (const float4*)(x + i * 16);
#pragma unroll
    for (int g = 0; g < 4; g++) {
      float4 v = xi[g];
      acc[g * 4 + 0] += v.x; acc[g * 4 + 1] += v.y; acc[g * 4 + 2] += v.z; acc[g * 4 + 3] += v.w;
    }
  }

  int r0 = row_start[i], r1 = row_start[i + 1];
  for (int r = r0 + sub; r < r1; r += 4) {
    int j = csr[r];
    const float4* xj = (const float4*)(x + j * 16);
#pragma unroll
    for (int g = 0; g < 4; g++) {
      float4 v = xj[g];
      acc[g * 4 + 0] += v.x; acc[g * 4 + 1] += v.y; acc[g * 4 + 2] += v.z; acc[g * 4 + 3] += v.w;
    }
  }

#pragma unroll
  for (int k = 0; k < 16; k++) {
    float v = acc[k];
    v += __shfl_xor(v, 1);
    v += __shfl_xor(v, 2);
    acc[k] = v;
  }

  float invdeg = 1.0f / (float)(r1 - r0 + 1);
  {
    int og = sub;
    float s0 = 0.f, s1 = 0.f, s2 = 0.f, s3 = 0.f;
#pragma unroll
    for (int k = 0; k < 16; k++) {
      float4 w = sW[k * 4 + og];
      float a = acc[k];
      s0 += a * w.x; s1 += a * w.y; s2 += a * w.z; s3 += a * w.w;
    }
    float o0 = s0 * invdeg + sb[og * 4 + 0];
    float o1 = s1 * invdeg + sb[og * 4 + 1];
    float o2 = s2 * invdeg + sb[og * 4 + 2];
    float o3 = s3 * invdeg + sb[og * 4 + 3];
    if (RELU) {
      o0 = fmaxf(o0, 0.f); o1 = fmaxf(o1, 0.f); o2 = fmaxf(o2, 0.f); o3 = fmaxf(o3, 0.f);
    }
    *(float4*)(out + i * 16 + og * 4) = make_float4(o0, o1, o2, o3);
  }
}

// ---------------- BatchNorm ----------------

__global__ void bn_stats_kernel(const float* __restrict__ x, float* __restrict__ stats, int n) {
  __shared__ float ss[32];
  int t = threadIdx.x;
  if (t < 32) ss[t] = 0.f;
  __syncthreads();
  float ls[16], lq[16];
#pragma unroll
  for (int k = 0; k < 16; k++) { ls[k] = 0.f; lq[k] = 0.f; }
  for (int i = blockIdx.x * blockDim.x + t; i < n; i += gridDim.x * blockDim.x) {
    const float4* xi = (const float4*)(x + i * 16);
#pragma unroll
    for (int g = 0; g < 4; g++) {
      float4 v = xi[g];
      ls[g * 4 + 0] += v.x; lq[g * 4 + 0] += v.x * v.x;
      ls[g * 4 + 1] += v.y; lq[g * 4 + 1] += v.y * v.y;
      ls[g * 4 + 2] += v.z; lq[g * 4 + 2] += v.z * v.z;
      ls[g * 4 + 3] += v.w; lq[g * 4 + 3] += v.w * v.w;
    }
  }
#pragma unroll
  for (int k = 0; k < 16; k++) {
    atomicAdd(&ss[k], ls[k]);
    atomicAdd(&ss[16 + k], lq[k]);
  }
  __syncthreads();
  if (t < 32) atomicAdd(&stats[t], ss[t]);
}

// RESID: out = relu(bn(x)) (+ r1 + r2 if RESID)
template <int RESID>
__global__ void bn_apply_kernel(const float* __restrict__ x, const float* __restrict__ stats,
                                const float* __restrict__ g, const float* __restrict__ be,
                                const float* __restrict__ r1, const float* __restrict__ r2,
                                float* __restrict__ out, int n) {
  __shared__ float sscale[16], sshift[16];
  int t = threadIdx.x;
  if (t < 16) {
    float invn = 1.0f / (float)n;
    float mu = stats[t] * invn;
    float var = stats[16 + t] * invn - mu * mu;
    float sc = g[t] * rsqrtf(var + 1e-5f);
    sscale[t] = sc;
    sshift[t] = be[t] - mu * sc;
  }
  __syncthreads();
  int i = blockIdx.x * blockDim.x + t;
  if (i >= n) return;
#pragma unroll
  for (int og = 0; og < 4; og++) {
    float4 v = *(const float4*)(x + i * 16 + og * 4);
    float o0 = fmaxf(v.x * sscale[og * 4 + 0] + sshift[og * 4 + 0], 0.f);
    float o1 = fmaxf(v.y * sscale[og * 4 + 1] + sshift[og * 4 + 1], 0.f);
    float o2 = fmaxf(v.z * sscale[og * 4 + 2] + sshift[og * 4 + 2], 0.f);
    float o3 = fmaxf(v.w * sscale[og * 4 + 3] + sshift[og * 4 + 3], 0.f);
    if (RESID) {
      float4 a = *(const float4*)(r1 + i * 16 + og * 4);
      float4 bb = *(const float4*)(r2 + i * 16 + og * 4);
      o0 += a.x + bb.x; o1 += a.y + bb.y; o2 += a.z + bb.z; o3 += a.w + bb.w;
    }
    *(float4*)(out + i * 16 + og * 4) = make_float4(o0, o1, o2, o3);
  }
}

// ---------------- MLP head: 16 ->64 relu ->64 relu ->16 relu ->1 sigmoid ----------------

__global__ void mlp_kernel(const float* __restrict__ h,
                           const float* __restrict__ lw1, const float* __restrict__ lb1,
                           const float* __restrict__ lw2, const float* __restrict__ lb2,
                           const float* __restrict__ lw3, const float* __restrict__ lb3,
                           const float* __restrict__ ow, const float* __restrict__ ob,
                           float* __restrict__ out, int n) {
  __shared__ float4 s1[256];   // 16x64
  __shared__ float4 s2[1024];  // 64x64
  __shared__ float4 s3[256];   // 64x16
  __shared__ float sb1[64], sb2[64], sb3[16], sow[16], sob[1];
  {
    int t = threadIdx.x;
    for (int k = t; k < 1024; k += blockDim.x) ((float*)s1)[k] = lw1[k];
    for (int k = t; k < 4096; k += blockDim.x) ((float*)s2)[k] = lw2[k];
    for (int k = t; k < 1024; k += blockDim.x) ((float*)s3)[k] = lw3[k];
    if (t < 64) sb1[t] = lb1[t];
    if (t < 64) sb2[t] = lb2[t];
    if (t < 16) sb3[t] = lb3[t];
    if (t < 16) sow[t] = ow[t];
    if (t == 0) sob[0] = ob[0];
  }
  __syncthreads();
  int i = blockIdx.x * blockDim.x + threadIdx.x;
  if (i >= n) return;

  float in16[16];
  const float4* hp = (const float4*)(h + i * 16);
#pragma unroll
  for (int g = 0; g < 4; g++) {
    float4 v = hp[g];
    in16[g * 4 + 0] = v.x; in16[g * 4 + 1] = v.y; in16[g * 4 + 2] = v.z; in16[g * 4 + 3] = v.w;
  }

  float a[64];
#pragma unroll
  for (int og = 0; og < 16; og++) {
    float s0 = sb1[og * 4 + 0], sy = sb1[og * 4 + 1], sz = sb1[og * 4 + 2], sw = sb1[og * 4 + 3];
#pragma unroll
    for (int k = 0; k < 16; k++) {
      float4 w = s1[k * 16 + og];
      float v = in16[k];
      s0 += v * w.x; sy += v * w.y; sz += v * w.z; sw += v * w.w;
    }
    a[og * 4 + 0] = fmaxf(s0, 0.f); a[og * 4 + 1] = fmaxf(sy, 0.f);
    a[og * 4 + 2] = fmaxf(sz, 0.f); a[og * 4 + 3] = fmaxf(sw, 0.f);
  }

  float b2[64];
#pragma unroll
  for (int og = 0; og < 16; og++) {
    float s0 = sb2[og * 4 + 0], sy = sb2[og * 4 + 1], sz = sb2[og * 4 + 2], sw = sb2[og * 4 + 3];
#pragma unroll
    for (int k = 0; k < 64; k++) {
      float4 w = s2[k * 16 + og];
      float v = a[k];
      s0 += v * w.x; sy += v * w.y; sz += v * w.z; sw += v * w.w;
    }
    b2[og * 4 + 0] = fmaxf(s0, 0.f); b2[og * 4 + 1] = fmaxf(sy, 0.f);
    b2[og * 4 + 2] = fmaxf(sz, 0.f); b2[og * 4 + 3] = fmaxf(sw, 0.f);
  }

  float c3[16];
#pragma unroll
  for (int og = 0; og < 4; og++) {
    float s0 = sb3[og * 4 + 0], sy = sb3[og * 4 + 1], sz = sb3[og * 4 + 2], sw = sb3[og * 4 + 3];
#pragma unroll
    for (int k = 0; k < 64; k++) {
      float4 w = s3[k * 4 + og];
      float v = b2[k];
      s0 += v * w.x; sy += v * w.y; sz += v * w.z; sw += v * w.w;
    }
    c3[og * 4 + 0] = fmaxf(s0, 0.f); c3[og * 4 + 1] = fmaxf(sy, 0.f);
    c3[og * 4 + 2] = fmaxf(sz, 0.f); c3[og * 4 + 3] = fmaxf(sw, 0.f);
  }

  float z = sob[0];
#pragma unroll
  for (int k = 0; k < 16; k++) z += c3[k] * sow[k];
  out[i] = 1.0f / (1.0f + __expf(-z));
}

// ---------------- launch ----------------

extern "C" void kernel_launch(void* const* d_in, const int* in_sizes, int n_in,
                              void* d_out, int out_size, void* d_ws, size_t ws_size,
                              hipStream_t stream) {
  const float* x = (const float*)d_in[0];
  const int* ei = (const int*)d_in[1];
  const int N = in_sizes[0] / 16;
  const int E = in_sizes[1] / 2;
  const int* srcp = ei;
  const int* dstp = ei + E;

  const float* W1 = (const float*)d_in[2];  const float* u1 = (const float*)d_in[3];
  const float* c1 = (const float*)d_in[4];  const float* b1 = (const float*)d_in[5];
  const float* W2 = (const float*)d_in[6];  const float* u2 = (const float*)d_in[7];
  const float* c2 = (const float*)d_in[8];  const float* b2 = (const float*)d_in[9];
  const float* W3 = (const float*)d_in[10]; const float* u3 = (const float*)d_in[11];
  const float* c3 = (const float*)d_in[12]; const float* b3 = (const float*)d_in[13];
  const float* W4 = (const float*)d_in[14]; const float* b4 = (const float*)d_in[17];
  const float* W5 = (const float*)d_in[18]; const float* b5 = (const float*)d_in[21];
  const float* W6 = (const float*)d_in[22]; const float* b6 = (const float*)d_in[25];
  const float* g1 = (const float*)d_in[26]; const float* be1 = (const float*)d_in[27];
  const float* g2 = (const float*)d_in[28]; const float* be2 = (const float*)d_in[29];
  const float* lw1 = (const float*)d_in[30]; const float* lb1 = (const float*)d_in[31];
  const float* lw2 = (const float*)d_in[32]; const float* lb2 = (const float*)d_in[33];
  const float* lw3 = (const float*)d_in[34]; const float* lb3 = (const float*)d_in[35];
  const float* ow = (const float*)d_in[36]; const float* ob = (const float*)d_in[37];
  float* out = (float*)d_out;

  char* ws = (char*)d_ws;
  size_t off = 0;
  auto alloc = [&](size_t bytes) -> void* {
    void* p = ws + off;
    off = (off + bytes + 255) & ~(size_t)255;
    return p;
  };
  int* row_start = (int*)alloc((size_t)(N + 1) * 4);
  int* csr = (int*)alloc((size_t)E * 4);
  float* xu = (float*)alloc((size_t)N * 4 * 4);
  float* bufA = (float*)alloc((size_t)N * 16 * 4);
  float* bufB = (float*)alloc((size_t)N * 16 * 4);
  float* h2b = (float*)alloc((size_t)N * 16 * 4);
  float* h4b = (float*)alloc((size_t)N * 16 * 4);
  float* tmp = (float*)alloc((size_t)N * 16 * 4);
  float* stats = (float*)alloc(32 * 4);
  const int NBUK = (N + (1 << BSHIFT) - 1) >> BSHIFT;
  int* bcnt = (int*)alloc((size_t)NBUK * 4);
  int* gbase = (int*)alloc((size_t)(NBUK + 1) * 4);
  int* gbcur = (int*)alloc((size_t)NBUK * 4);
  // pairs staging (E * 8B = 12.8MB) aliases bufA+bufB, which are contiguous
  // (N*16*4 = 6.4MB each, 256B-aligned with no gap) and unused until layer 1.
  int2* pairs = (int2*)bufA;

  const int NB = (N + BLK - 1) / BLK;       // node-parallel grid (1 thread/node)
  const int NG = (4 * N + BLK - 1) / BLK;   // gather grid (4 threads/node)
  const int NT = (E + TILE - 1) / TILE;     // edge tiles for binning kernels

  // ---- CSR build (per call; ws is re-poisoned every launch) ----
  hipMemsetAsync(bcnt, 0, (size_t)NBUK * 4, stream);
  bhist_kernel<<<NT, BLK, 0, stream>>>(dstp, bcnt, E, NBUK);
  bscan_kernel<<<1, BLK, 0, stream>>>(bcnt, gbase, gbcur, NBUK, E);
  scatter_pairs_lds_kernel<<<NT, BLK, 0, stream>>>(srcp, dstp, gbcur, pairs, E, NBUK);
  bucket_build_kernel<<<NBUK, BLK, 0, stream>>>(pairs, gbase, row_start, csr, N, NBUK, E);

  // ---- Layer 1: h = relu(feast4(x)) -> bufA ----
  xu4_kernel<<<NB, BLK, 0, stream>>>(x, u1, xu, N);
  gather4_kernel<0><<<NG, BLK, 0, stream>>>(x, xu, row_start, csr, W1, c1, b1, bufA, nullptr, N);

  // ---- Layer 2: h2 = feast4(bufA) (raw -> h2b), relu -> bufB ----
  xu4_kernel<<<NB, BLK, 0, stream>>>(bufA, u2, xu, N);
  gather4_kernel<2><<<NG, BLK, 0, stream>>>(bufA, xu, row_start, csr, W2, c2, b2, bufB, h2b, N);

  // ---- Layer 3: h3 = relu(bn(feast4(bufB))) -> bufA ----
  xu4_kernel<<<NB, BLK, 0, stream>>>(bufB, u3, xu, N);
  gather4_kernel<1><<<NG, BLK, 0, stream>>>(bufB, xu, row_start, csr, W3, c3, b3, tmp, nullptr, N);
  hipMemsetAsync(stats, 0, 32 * 4, stream);
  bn_stats_kernel<<<256, BLK, 0, stream>>>(tmp, stats, N);
  bn_apply_kernel<0><<<NB, BLK, 0, stream>>>(tmp, stats, g1, be1, nullptr, nullptr, bufA, N);

  // ---- Layer 4: h4 = relu(feast1(bufA)) -> h4b ----
  gather1_kernel<1><<<NG, BLK, 0, stream>>>(bufA, row_start, csr, W4, b4, h4b, N);

  // ---- Layer 5: h5 = relu(feast1(h4b)) -> bufB ----
  gather1_kernel<1><<<NG, BLK, 0, stream>>>(h4b, row_start, csr, W5, b5, bufB, N);

  // ---- Layer 6: h6 = relu(bn(feast1(bufB))) + h2b + h4b -> bufA ----
  gather1_kernel<0><<<NG, BLK, 0, stream>>>(bufB, row_start, csr, W6, b6, tmp, N);
  hipMemsetAsync(stats, 0, 32 * 4, stream);
  bn_stats_kernel<<<256, BLK, 0, stream>>>(tmp, stats, N);
  bn_apply_kernel<1><<<NB, BLK, 0, stream>>>(tmp, stats, g2, be2, h2b, h4b, bufA, N);

  // ---- MLP head -> out ----
  mlp_kernel<<<NB, BLK, 0, stream>>>(bufA, lw1, lb1, lw2, lb2, lw3, lb3, ow, ob, out, N);
}

// Round 4
// 614.403 us; speedup vs baseline: 1.2734x; 1.1216x over previous
//
#include <hip/hip_runtime.h>
#include <cmath>

#define BLK 256
#define BSHIFT 9          // 512 nodes per bucket; ~8K edges (~65KB pairs) per bucket
#define EPT 16            // edges per thread in binning kernels
#define TILE (BLK * EPT)  // 4096 edges per tile

// ---------------- CSR build: LDS-binned bucket scatter ----------------

// Pass 0: per-tile LDS histogram of dst buckets -> global bucket counts.
__global__ void bhist_kernel(const int* __restrict__ dst, int* __restrict__ bcnt,
                             int E, int nbuk) {
  __shared__ int hist[256];
  int t = threadIdx.x;
  hist[t] = 0;
  __syncthreads();
  int base = blockIdx.x * TILE;
#pragma unroll
  for (int k = 0; k < EPT; k++) {
    int e = base + k * BLK + t;
    if (e < E) atomicAdd(&hist[dst[e] >> BSHIFT], 1);
  }
  __syncthreads();
  if (t < nbuk && hist[t] > 0) atomicAdd(&bcnt[t], hist[t]);
}

// 1-block exclusive scan over bucket counts -> gbase (bases) and gbcur (cursors).
__global__ void bscan_kernel(const int* __restrict__ bcnt, int* __restrict__ gbase,
                             int* __restrict__ gbcur, int nbuk, int E) {
  __shared__ int sdata[BLK];
  int t = threadIdx.x;
  int v = (t < nbuk) ? bcnt[t] : 0;
  sdata[t] = v;
  __syncthreads();
  for (int off = 1; off < BLK; off <<= 1) {
    int x = (t >= off) ? sdata[t - off] : 0;
    __syncthreads();
    sdata[t] += x;
    __syncthreads();
  }
  int excl = sdata[t] - v;
  if (t < nbuk) { gbase[t] = excl; gbcur[t] = excl; }
  if (t == 0) gbase[nbuk] = E;
}

// Pass 1: LDS-binned scatter. Each tile reserves ONE contiguous chunk per bucket
// (single global atomicAdd) and writes each bucket's edges as a contiguous burst.
__global__ void scatter_pairs_lds_kernel(const int* __restrict__ src, const int* __restrict__ dst,
                                         int* __restrict__ gbcur, int2* __restrict__ pairs,
                                         int E, int nbuk) {
  __shared__ int hist[256];
  __shared__ int chunk[256];
  int t = threadIdx.x;
  hist[t] = 0;
  __syncthreads();
  int base = blockIdx.x * TILE;
  int es[EPT], ed[EPT];
#pragma unroll
  for (int k = 0; k < EPT; k++) {
    int e = base + k * BLK + t;
    if (e < E) {
      es[k] = src[e];
      ed[k] = dst[e];
      atomicAdd(&hist[ed[k] >> BSHIFT], 1);
    } else {
      ed[k] = -1;
    }
  }
  __syncthreads();
  if (t < nbuk && hist[t] > 0) chunk[t] = atomicAdd(&gbcur[t], hist[t]);
  __syncthreads();
#pragma unroll
  for (int k = 0; k < EPT; k++) {
    if (ed[k] >= 0) {
      int p = atomicAdd(&chunk[ed[k] >> BSHIFT], 1);
      pairs[p] = make_int2(es[k], ed[k]);
    }
  }
}

// Pass 2: one block per bucket. Per-node counts + exclusive scan entirely in LDS,
// writes row_start slice, then scatters csr within its own ~32KB region.
__global__ void bucket_build_kernel(const int2* __restrict__ pairs, const int* __restrict__ gbase,
                                    int* __restrict__ row_start, int* __restrict__ csr,
                                    int n, int nbuk, int E) {
  __shared__ int cnt[512];
  __shared__ int excl[512];
  __shared__ int s2[BLK];
  int b = blockIdx.x;
  int t = threadIdx.x;
  int n0 = b << BSHIFT;
  int n1 = min(n0 + (1 << BSHIFT), n);
  int bb0 = gbase[b], bb1 = gbase[b + 1];
  cnt[t] = 0; cnt[t + 256] = 0;
  __syncthreads();
  for (int r = bb0 + t; r < bb1; r += BLK) atomicAdd(&cnt[pairs[r].y - n0], 1);
  __syncthreads();
  // pairwise sums then 256-wide scan
  s2[t] = cnt[2 * t] + cnt[2 * t + 1];
  __syncthreads();
  int v = s2[t];
  for (int off = 1; off < BLK; off <<= 1) {
    int x = (t >= off) ? s2[t - off] : 0;
    __syncthreads();
    s2[t] += x;
    __syncthreads();
  }
  int e2 = s2[t] - v;  // exclusive over pair-sums
  excl[2 * t] = e2;
  excl[2 * t + 1] = e2 + cnt[2 * t];
  __syncthreads();
  // row_start for this bucket's nodes
  for (int k = t; k < n1 - n0; k += BLK) row_start[n0 + k] = bb0 + excl[k];
  if (b == nbuk - 1 && t == 0) row_start[n] = E;
  // reuse cnt[] as global-position cursors
  cnt[2 * t] = bb0 + excl[2 * t];
  cnt[2 * t + 1] = bb0 + excl[2 * t + 1];
  __syncthreads();
  for (int r = bb0 + t; r < bb1; r += BLK) {
    int2 pr = pairs[r];
    int pos = atomicAdd(&cnt[pr.y - n0], 1);
    csr[pos] = pr.x;
  }
}

// ---------------- FeaSt heads=4 ----------------

// xu[i,h] = sum_k x[i,k] * u[k,h]   (u is 16x4 row-major)
__global__ void xu4_kernel(const float* __restrict__ x, const float* __restrict__ u,
                           float* __restrict__ xu, int n) {
  __shared__ float su[64];
  if (threadIdx.x < 64) su[threadIdx.x] = u[threadIdx.x];
  __syncthreads();
  int i = blockIdx.x * blockDim.x + threadIdx.x;
  if (i >= n) return;
  const float4* xi = (const float4*)(x + i * 16);
  float a0 = 0.f, a1 = 0.f, a2 = 0.f, a3 = 0.f;
#pragma unroll
  for (int g = 0; g < 4; g++) {
    float4 v = xi[g];
    a0 += v.x * su[(g*4+0)*4+0] + v.y * su[(g*4+1)*4+0] + v.z * su[(g*4+2)*4+0] + v.w * su[(g*4+3)*4+0];
    a1 += v.x * su[(g*4+0)*4+1] + v.y * su[(g*4+1)*4+1] + v.z * su[(g*4+2)*4+1] + v.w * su[(g*4+3)*4+1];
    a2 += v.x * su[(g*4+0)*4+2] + v.y * su[(g*4+1)*4+2] + v.z * su[(g*4+2)*4+2] + v.w * su[(g*4+3)*4+2];
    a3 += v.x * su[(g*4+0)*4+3] + v.y * su[(g*4+1)*4+3] + v.z * su[(g*4+2)*4+3] + v.w * su[(g*4+3)*4+3];
  }
  *(float4*)(xu + i * 4) = make_float4(a0, a1, a2, a3);
}

// 4 threads per node. sub = tid&3 handles neighbors r0+sub, r0+sub+4, ...
// acc quad-reduced via shfl_xor; each sub-lane emits output float4 #sub.
// EPI: 0 = relu->out ; 1 = raw->out ; 2 = raw->out2 AND relu->out
template <int EPI>
__global__ void gather4_kernel(const float* __restrict__ x, const float* __restrict__ xu,
                               const int* __restrict__ row_start, const int* __restrict__ csr,
                               const float* __restrict__ W, const float* __restrict__ c,
                               const float* __restrict__ b,
                               float* __restrict__ out, float* __restrict__ out2, int n) {
  __shared__ float4 sW[256];  // W: 16 x 64 row-major; float4 idx = k*16 + h*4 + og
  __shared__ float sc[4];
  __shared__ float sb[16];
  {
    int t = threadIdx.x;
    for (int k = t; k < 1024; k += blockDim.x) ((float*)sW)[k] = W[k];
    if (t < 4) sc[t] = c[t];
    if (t < 16) sb[t] = b[t];
  }
  __syncthreads();
  int tid = blockIdx.x * blockDim.x + threadIdx.x;
  int i = tid >> 2;
  int sub = tid & 3;
  if (i >= n) return;

  float4 xui = *(const float4*)(xu + i * 4);
  float acc[4][16];
#pragma unroll
  for (int h = 0; h < 4; h++)
#pragma unroll
    for (int k = 0; k < 16; k++) acc[h][k] = 0.f;

  // self loop: logits = c  ->  q = softmax(c). Assigned to sub 3 (lightest tail).
  if (sub == 3) {
    float m = fmaxf(fmaxf(sc[0], sc[1]), fmaxf(sc[2], sc[3]));
    float e0 = __expf(sc[0] - m), e1 = __expf(sc[1] - m), e2 = __expf(sc[2] - m), e3 = __expf(sc[3] - m);
    float inv = 1.0f / (e0 + e1 + e2 + e3);
    float q[4] = {e0 * inv, e1 * inv, e2 * inv, e3 * inv};
    const float4* xi = (const float4*)(x + i * 16);
#pragma unroll
    for (int g = 0; g < 4; g++) {
      float4 v = xi[g];
#pragma unroll
      for (int h = 0; h < 4; h++) {
        acc[h][g * 4 + 0] += q[h] * v.x;
        acc[h][g * 4 + 1] += q[h] * v.y;
        acc[h][g * 4 + 2] += q[h] * v.z;
        acc[h][g * 4 + 3] += q[h] * v.w;
      }
    }
  }

  int r0 = row_start[i], r1 = row_start[i + 1];
  for (int r = r0 + sub; r < r1; r += 4) {
    int j = csr[r];
    float4 xuj = *(const float4*)(xu + j * 4);
    float l0 = xuj.x - xui.x + sc[0];
    float l1 = xuj.y - xui.y + sc[1];
    float l2 = xuj.z - xui.z + sc[2];
    float l3 = xuj.w - xui.w + sc[3];
    float m = fmaxf(fmaxf(l0, l1), fmaxf(l2, l3));
    float e0 = __expf(l0 - m), e1 = __expf(l1 - m), e2 = __expf(l2 - m), e3 = __expf(l3 - m);
    float inv = 1.0f / (e0 + e1 + e2 + e3);
    float q0 = e0 * inv, q1 = e1 * inv, q2 = e2 * inv, q3 = e3 * inv;
    const float4* xj = (const float4*)(x + j * 16);
#pragma unroll
    for (int g = 0; g < 4; g++) {
      float4 v = xj[g];
      acc[0][g * 4 + 0] += q0 * v.x; acc[0][g * 4 + 1] += q0 * v.y; acc[0][g * 4 + 2] += q0 * v.z; acc[0][g * 4 + 3] += q0 * v.w;
      acc[1][g * 4 + 0] += q1 * v.x; acc[1][g * 4 + 1] += q1 * v.y; acc[1][g * 4 + 2] += q1 * v.z; acc[1][g * 4 + 3] += q1 * v.w;
      acc[2][g * 4 + 0] += q2 * v.x; acc[2][g * 4 + 1] += q2 * v.y; acc[2][g * 4 + 2] += q2 * v.z; acc[2][g * 4 + 3] += q2 * v.w;
      acc[3][g * 4 + 0] += q3 * v.x; acc[3][g * 4 + 1] += q3 * v.y; acc[3][g * 4 + 2] += q3 * v.z; acc[3][g * 4 + 3] += q3 * v.w;
    }
  }

  // quad reduction (lanes {4m,4m+1,4m+2,4m+3} hold partials of node i)
#pragma unroll
  for (int h = 0; h < 4; h++)
#pragma unroll
    for (int k = 0; k < 16; k++) {
      float v = acc[h][k];
      v += __shfl_xor(v, 1);
      v += __shfl_xor(v, 2);
      acc[h][k] = v;
    }

  float invdeg = 1.0f / (float)(r1 - r0 + 1);
  // each sub-lane computes output float4 #sub
  {
    int og = sub;
    float s0 = 0.f, s1 = 0.f, s2 = 0.f, s3 = 0.f;
#pragma unroll
    for (int k = 0; k < 16; k++) {
#pragma unroll
      for (int h = 0; h < 4; h++) {
        float4 w = sW[k * 16 + h * 4 + og];
        float a = acc[h][k];
        s0 += a * w.x; s1 += a * w.y; s2 += a * w.z; s3 += a * w.w;
      }
    }
    float o0 = s0 * invdeg + sb[og * 4 + 0];
    float o1 = s1 * invdeg + sb[og * 4 + 1];
    float o2 = s2 * invdeg + sb[og * 4 + 2];
    float o3 = s3 * invdeg + sb[og * 4 + 3];
    if (EPI == 1) {
      *(float4*)(out + i * 16 + og * 4) = make_float4(o0, o1, o2, o3);
    } else if (EPI == 0) {
      *(float4*)(out + i * 16 + og * 4) =
          make_float4(fmaxf(o0, 0.f), fmaxf(o1, 0.f), fmaxf(o2, 0.f), fmaxf(o3, 0.f));
    } else {
      *(float4*)(out2 + i * 16 + og * 4) = make_float4(o0, o1, o2, o3);
      *(float4*)(out + i * 16 + og * 4) =
          make_float4(fmaxf(o0, 0.f), fmaxf(o1, 0.f), fmaxf(o2, 0.f), fmaxf(o3, 0.f));
    }
  }
}

// ---------------- FeaSt heads=1 (softmax over 1 head == 1: pure mean agg + matvec) ----------------
// 4 threads per node, same decomposition as gather4.

template <int RELU>
__global__ void gather1_kernel(const float* __restrict__ x, const int* __restrict__ row_start,
                               const int* __restrict__ csr, const float* __restrict__ W,
                               const float* __restrict__ b, float* __restrict__ out, int n) {
  __shared__ float4 sW[64];  // 16x16, float4 idx = k*4+og
  __shared__ float sb[16];
  {
    int t = threadIdx.x;
    for (int k = t; k < 256; k += blockDim.x) ((float*)sW)[k] = W[k];
    if (t < 16) sb[t] = b[t];
  }
  __syncthreads();
  int tid = blockIdx.x * blockDim.x + threadIdx.x;
  int i = tid >> 2;
  int sub = tid & 3;
  if (i >= n) return;

  float acc[16];
#pragma unroll
  for (int k = 0; k < 16; k++) acc[k] = 0.f;

  if (sub == 3) {  // self loop
    const float4* xi = (const float4*)(x + i * 16);
#pragma unroll
    for (int g = 0; g < 4; g++) {
      float4 v = xi[g];
      acc[g * 4 + 0] += v.x; acc[g * 4 + 1] += v.y; acc[g * 4 + 2] += v.z; acc[g * 4 + 3] += v.w;
    }
  }

  int r0 = row_start[i], r1 = row_start[i + 1];
  for (int r = r0 + sub; r < r1; r += 4) {
    int j = csr[r];
    const float4* xj = (const float4*)(x + j * 16);
#pragma unroll
    for (int g = 0; g < 4; g++) {
      float4 v = xj[g];
      acc[g * 4 + 0] += v.x; acc[g * 4 + 1] += v.y; acc[g * 4 + 2] += v.z; acc[g * 4 + 3] += v.w;
    }
  }

#pragma unroll
  for (int k = 0; k < 16; k++) {
    float v = acc[k];
    v += __shfl_xor(v, 1);
    v += __shfl_xor(v, 2);
    acc[k] = v;
  }

  float invdeg = 1.0f / (float)(r1 - r0 + 1);
  {
    int og = sub;
    float s0 = 0.f, s1 = 0.f, s2 = 0.f, s3 = 0.f;
#pragma unroll
    for (int k = 0; k < 16; k++) {
      float4 w = sW[k * 4 + og];
      float a = acc[k];
      s0 += a * w.x; s1 += a * w.y; s2 += a * w.z; s3 += a * w.w;
    }
    float o0 = s0 * invdeg + sb[og * 4 + 0];
    float o1 = s1 * invdeg + sb[og * 4 + 1];
    float o2 = s2 * invdeg + sb[og * 4 + 2];
    float o3 = s3 * invdeg + sb[og * 4 + 3];
    if (RELU) {
      o0 = fmaxf(o0, 0.f); o1 = fmaxf(o1, 0.f); o2 = fmaxf(o2, 0.f); o3 = fmaxf(o3, 0.f);
    }
    *(float4*)(out + i * 16 + og * 4) = make_float4(o0, o1, o2, o3);
  }
}

// ---------------- BatchNorm ----------------

__global__ void bn_stats_kernel(const float* __restrict__ x, float* __restrict__ stats, int n) {
  __shared__ float ss[32];
  int t = threadIdx.x;
  if (t < 32) ss[t] = 0.f;
  __syncthreads();
  float ls[16], lq[16];
#pragma unroll
  for (int k = 0; k < 16; k++) { ls[k] = 0.f; lq[k] = 0.f; }
  for (int i = blockIdx.x * blockDim.x + t; i < n; i += gridDim.x * blockDim.x) {
    const float4* xi = (const float4*)(x + i * 16);
#pragma unroll
    for (int g = 0; g < 4; g++) {
      float4 v = xi[g];
      ls[g * 4 + 0] += v.x; lq[g * 4 + 0] += v.x * v.x;
      ls[g * 4 + 1] += v.y; lq[g * 4 + 1] += v.y * v.y;
      ls[g * 4 + 2] += v.z; lq[g * 4 + 2] += v.z * v.z;
      ls[g * 4 + 3] += v.w; lq[g * 4 + 3] += v.w * v.w;
    }
  }
#pragma unroll
  for (int k = 0; k < 16; k++) {
    atomicAdd(&ss[k], ls[k]);
    atomicAdd(&ss[16 + k], lq[k]);
  }
  __syncthreads();
  if (t < 32) atomicAdd(&stats[t], ss[t]);
}

// RESID: out = relu(bn(x)) (+ r1 + r2 if RESID)
template <int RESID>
__global__ void bn_apply_kernel(const float* __restrict__ x, const float* __restrict__ stats,
                                const float* __restrict__ g, const float* __restrict__ be,
                                const float* __restrict__ r1, const float* __restrict__ r2,
                                float* __restrict__ out, int n) {
  __shared__ float sscale[16], sshift[16];
  int t = threadIdx.x;
  if (t < 16) {
    float invn = 1.0f / (float)n;
    float mu = stats[t] * invn;
    float var = stats[16 + t] * invn - mu * mu;
    float sc = g[t] * rsqrtf(var + 1e-5f);
    sscale[t] = sc;
    sshift[t] = be[t] - mu * sc;
  }
  __syncthreads();
  int i = blockIdx.x * blockDim.x + t;
  if (i >= n) return;
#pragma unroll
  for (int og = 0; og < 4; og++) {
    float4 v = *(const float4*)(x + i * 16 + og * 4);
    float o0 = fmaxf(v.x * sscale[og * 4 + 0] + sshift[og * 4 + 0], 0.f);
    float o1 = fmaxf(v.y * sscale[og * 4 + 1] + sshift[og * 4 + 1], 0.f);
    float o2 = fmaxf(v.z * sscale[og * 4 + 2] + sshift[og * 4 + 2], 0.f);
    float o3 = fmaxf(v.w * sscale[og * 4 + 3] + sshift[og * 4 + 3], 0.f);
    if (RESID) {
      float4 a = *(const float4*)(r1 + i * 16 + og * 4);
      float4 bb = *(const float4*)(r2 + i * 16 + og * 4);
      o0 += a.x + bb.x; o1 += a.y + bb.y; o2 += a.z + bb.z; o3 += a.w + bb.w;
    }
    *(float4*)(out + i * 16 + og * 4) = make_float4(o0, o1, o2, o3);
  }
}

// ---------------- MLP head: 16 ->64 relu ->64 relu ->16 relu ->1 sigmoid ----------------
// 4 threads per node; lane sub owns activations [sub*16, sub*16+16) of each 64-wide
// layer (16 VGPRs, no spill — the 1-thread version spilled a[64]+b2[64] to scratch
// at VGPR=64 and ran 103us at 16% occupancy). Cross-lane operands via width-4 shfl.

__global__ void mlp_kernel(const float* __restrict__ h,
                           const float* __restrict__ lw1, const float* __restrict__ lb1,
                           const float* __restrict__ lw2, const float* __restrict__ lb2,
                           const float* __restrict__ lw3, const float* __restrict__ lb3,
                           const float* __restrict__ ow, const float* __restrict__ ob,
                           float* __restrict__ out, int n) {
  __shared__ float4 s1[256];   // 16x64, float4 idx = k*16 + og
  __shared__ float4 s2[1024];  // 64x64, float4 idx = k*16 + og
  __shared__ float4 s3[256];   // 64x16, float4 idx = k*4 + og
  __shared__ float sb1[64], sb2[64], sb3[16], sow[16], sob[1];
  {
    int t = threadIdx.x;
    for (int k = t; k < 1024; k += blockDim.x) ((float*)s1)[k] = lw1[k];
    for (int k = t; k < 4096; k += blockDim.x) ((float*)s2)[k] = lw2[k];
    for (int k = t; k < 1024; k += blockDim.x) ((float*)s3)[k] = lw3[k];
    if (t < 64) sb1[t] = lb1[t];
    if (t < 64) sb2[t] = lb2[t];
    if (t < 16) sb3[t] = lb3[t];
    if (t < 16) sow[t] = ow[t];
    if (t == 0) sob[0] = ob[0];
  }
  __syncthreads();
  int tid = blockIdx.x * blockDim.x + threadIdx.x;
  int i = tid >> 2;
  int sub = tid & 3;
  if (i >= n) return;

  // each lane loads its quarter of the input (wave covers 16 nodes x 64B contiguous)
  float4 inq = *(const float4*)(h + i * 16 + sub * 4);
  float in4[4] = {inq.x, inq.y, inq.z, inq.w};

  // ---- L1: 16 -> 64, lane sub computes outputs [sub*16, sub*16+16) ----
  float a[16];
#pragma unroll
  for (int g = 0; g < 4; g++) {
    int og = sub * 4 + g;
    a[g * 4 + 0] = sb1[og * 4 + 0]; a[g * 4 + 1] = sb1[og * 4 + 1];
    a[g * 4 + 2] = sb1[og * 4 + 2]; a[g * 4 + 3] = sb1[og * 4 + 3];
  }
#pragma unroll
  for (int k = 0; k < 16; k++) {
    float v = __shfl(in4[k & 3], k >> 2, 4);
#pragma unroll
    for (int g = 0; g < 4; g++) {
      float4 w = s1[k * 16 + sub * 4 + g];
      a[g * 4 + 0] += v * w.x; a[g * 4 + 1] += v * w.y;
      a[g * 4 + 2] += v * w.z; a[g * 4 + 3] += v * w.w;
    }
  }
#pragma unroll
  for (int k = 0; k < 16; k++) a[k] = fmaxf(a[k], 0.f);

  // ---- L2: 64 -> 64, lane sub computes outputs [sub*16, sub*16+16) ----
  float b2[16];
#pragma unroll
  for (int g = 0; g < 4; g++) {
    int og = sub * 4 + g;
    b2[g * 4 + 0] = sb2[og * 4 + 0]; b2[g * 4 + 1] = sb2[og * 4 + 1];
    b2[g * 4 + 2] = sb2[og * 4 + 2]; b2[g * 4 + 3] = sb2[og * 4 + 3];
  }
#pragma unroll
  for (int k = 0; k < 64; k++) {
    float v = __shfl(a[k & 15], k >> 4, 4);
#pragma unroll
    for (int g = 0; g < 4; g++) {
      float4 w = s2[k * 16 + sub * 4 + g];
      b2[g * 4 + 0] += v * w.x; b2[g * 4 + 1] += v * w.y;
      b2[g * 4 + 2] += v * w.z; b2[g * 4 + 3] += v * w.w;
    }
  }
#pragma unroll
  for (int k = 0; k < 16; k++) b2[k] = fmaxf(b2[k], 0.f);

  // ---- L3: 64 -> 16, lane sub computes outputs [sub*4, sub*4+4) ----
  float c0 = sb3[sub * 4 + 0], c1 = sb3[sub * 4 + 1], c2 = sb3[sub * 4 + 2], c3v = sb3[sub * 4 + 3];
#pragma unroll
  for (int k = 0; k < 64; k++) {
    float v = __shfl(b2[k & 15], k >> 4, 4);
    float4 w = s3[k * 4 + sub];
    c0 += v * w.x; c1 += v * w.y; c2 += v * w.z; c3v += v * w.w;
  }
  c0 = fmaxf(c0, 0.f); c1 = fmaxf(c1, 0.f); c2 = fmaxf(c2, 0.f); c3v = fmaxf(c3v, 0.f);

  // ---- out: 16 -> 1 sigmoid (quad reduce) ----
  float zp = c0 * sow[sub * 4 + 0] + c1 * sow[sub * 4 + 1] +
             c2 * sow[sub * 4 + 2] + c3v * sow[sub * 4 + 3];
  zp += __shfl_xor(zp, 1);
  zp += __shfl_xor(zp, 2);
  if (sub == 0) out[i] = 1.0f / (1.0f + __expf(-(zp + sob[0])));
}

// ---------------- launch ----------------

extern "C" void kernel_launch(void* const* d_in, const int* in_sizes, int n_in,
                              void* d_out, int out_size, void* d_ws, size_t ws_size,
                              hipStream_t stream) {
  const float* x = (const float*)d_in[0];
  const int* ei = (const int*)d_in[1];
  const int N = in_sizes[0] / 16;
  const int E = in_sizes[1] / 2;
  const int* srcp = ei;
  const int* dstp = ei + E;

  const float* W1 = (const float*)d_in[2];  const float* u1 = (const float*)d_in[3];
  const float* c1 = (const float*)d_in[4];  const float* b1 = (const float*)d_in[5];
  const float* W2 = (const float*)d_in[6];  const float* u2 = (const float*)d_in[7];
  const float* c2 = (const float*)d_in[8];  const float* b2 = (const float*)d_in[9];
  const float* W3 = (const float*)d_in[10]; const float* u3 = (const float*)d_in[11];
  const float* c3 = (const float*)d_in[12]; const float* b3 = (const float*)d_in[13];
  const float* W4 = (const float*)d_in[14]; const float* b4 = (const float*)d_in[17];
  const float* W5 = (const float*)d_in[18]; const float* b5 = (const float*)d_in[21];
  const float* W6 = (const float*)d_in[22]; const float* b6 = (const float*)d_in[25];
  const float* g1 = (const float*)d_in[26]; const float* be1 = (const float*)d_in[27];
  const float* g2 = (const float*)d_in[28]; const float* be2 = (const float*)d_in[29];
  const float* lw1 = (const float*)d_in[30]; const float* lb1 = (const float*)d_in[31];
  const float* lw2 = (const float*)d_in[32]; const float* lb2 = (const float*)d_in[33];
  const float* lw3 = (const float*)d_in[34]; const float* lb3 = (const float*)d_in[35];
  const float* ow = (const float*)d_in[36]; const float* ob = (const float*)d_in[37];
  float* out = (float*)d_out;

  char* ws = (char*)d_ws;
  size_t off = 0;
  auto alloc = [&](size_t bytes) -> void* {
    void* p = ws + off;
    off = (off + bytes + 255) & ~(size_t)255;
    return p;
  };
  int* row_start = (int*)alloc((size_t)(N + 1) * 4);
  int* csr = (int*)alloc((size_t)E * 4);
  float* xu = (float*)alloc((size_t)N * 4 * 4);
  float* bufA = (float*)alloc((size_t)N * 16 * 4);
  float* bufB = (float*)alloc((size_t)N * 16 * 4);
  float* h2b = (float*)alloc((size_t)N * 16 * 4);
  float* h4b = (float*)alloc((size_t)N * 16 * 4);
  float* tmp = (float*)alloc((size_t)N * 16 * 4);
  float* stats = (float*)alloc(32 * 4);
  const int NBUK = (N + (1 << BSHIFT) - 1) >> BSHIFT;
  int* bcnt = (int*)alloc((size_t)NBUK * 4);
  int* gbase = (int*)alloc((size_t)(NBUK + 1) * 4);
  int* gbcur = (int*)alloc((size_t)NBUK * 4);
  // pairs staging (E * 8B = 12.8MB) aliases bufA+bufB, which are contiguous
  // (N*16*4 = 6.4MB each, 256B-aligned with no gap) and unused until layer 1.
  int2* pairs = (int2*)bufA;

  const int NB = (N + BLK - 1) / BLK;       // node-parallel grid (1 thread/node)
  const int NG = (4 * N + BLK - 1) / BLK;   // 4-threads-per-node grid
  const int NT = (E + TILE - 1) / TILE;     // edge tiles for binning kernels

  // ---- CSR build (per call; ws is re-poisoned every launch) ----
  hipMemsetAsync(bcnt, 0, (size_t)NBUK * 4, stream);
  bhist_kernel<<<NT, BLK, 0, stream>>>(dstp, bcnt, E, NBUK);
  bscan_kernel<<<1, BLK, 0, stream>>>(bcnt, gbase, gbcur, NBUK, E);
  scatter_pairs_lds_kernel<<<NT, BLK, 0, stream>>>(srcp, dstp, gbcur, pairs, E, NBUK);
  bucket_build_kernel<<<NBUK, BLK, 0, stream>>>(pairs, gbase, row_start, csr, N, NBUK, E);

  // ---- Layer 1: h = relu(feast4(x)) -> bufA ----
  xu4_kernel<<<NB, BLK, 0, stream>>>(x, u1, xu, N);
  gather4_kernel<0><<<NG, BLK, 0, stream>>>(x, xu, row_start, csr, W1, c1, b1, bufA, nullptr, N);

  // ---- Layer 2: h2 = feast4(bufA) (raw -> h2b), relu -> bufB ----
  xu4_kernel<<<NB, BLK, 0, stream>>>(bufA, u2, xu, N);
  gather4_kernel<2><<<NG, BLK, 0, stream>>>(bufA, xu, row_start, csr, W2, c2, b2, bufB, h2b, N);

  // ---- Layer 3: h3 = relu(bn(feast4(bufB))) -> bufA ----
  xu4_kernel<<<NB, BLK, 0, stream>>>(bufB, u3, xu, N);
  gather4_kernel<1><<<NG, BLK, 0, stream>>>(bufB, xu, row_start, csr, W3, c3, b3, tmp, nullptr, N);
  hipMemsetAsync(stats, 0, 32 * 4, stream);
  bn_stats_kernel<<<256, BLK, 0, stream>>>(tmp, stats, N);
  bn_apply_kernel<0><<<NB, BLK, 0, stream>>>(tmp, stats, g1, be1, nullptr, nullptr, bufA, N);

  // ---- Layer 4: h4 = relu(feast1(bufA)) -> h4b ----
  gather1_kernel<1><<<NG, BLK, 0, stream>>>(bufA, row_start, csr, W4, b4, h4b, N);

  // ---- Layer 5: h5 = relu(feast1(h4b)) -> bufB ----
  gather1_kernel<1><<<NG, BLK, 0, stream>>>(h4b, row_start, csr, W5, b5, bufB, N);

  // ---- Layer 6: h6 = relu(bn(feast1(bufB))) + h2b + h4b -> bufA ----
  gather1_kernel<0><<<NG, BLK, 0, stream>>>(bufB, row_start, csr, W6, b6, tmp, N);
  hipMemsetAsync(stats, 0, 32 * 4, stream);
  bn_stats_kernel<<<256, BLK, 0, stream>>>(tmp, stats, N);
  bn_apply_kernel<1><<<NB, BLK, 0, stream>>>(tmp, stats, g2, be2, h2b, h4b, bufA, N);

  // ---- MLP head -> out ----
  mlp_kernel<<<NG, BLK, 0, stream>>>(bufA, lw1, lb1, lw2, lb2, lw3, lb3, ow, ob, out, N);
}

// Round 5
// 506.538 us; speedup vs baseline: 1.5445x; 1.2129x over previous
//
#include <hip/hip_runtime.h>
#include <cmath>

#define BLK 256
#define BSHIFT 9          // 512 nodes per bucket; ~8K edges (~65KB pairs) per bucket
#define EPT 16            // edges per thread in binning kernels
#define TILE (BLK * EPT)  // 4096 edges per tile

// ---------------- CSR build: LDS-binned bucket scatter ----------------

// Pass 0: per-tile LDS histogram of dst buckets -> global bucket counts.
__global__ void bhist_kernel(const int* __restrict__ dst, int* __restrict__ bcnt,
                             int E, int nbuk) {
  __shared__ int hist[256];
  int t = threadIdx.x;
  hist[t] = 0;
  __syncthreads();
  int base = blockIdx.x * TILE;
#pragma unroll
  for (int k = 0; k < EPT; k++) {
    int e = base + k * BLK + t;
    if (e < E) atomicAdd(&hist[dst[e] >> BSHIFT], 1);
  }
  __syncthreads();
  if (t < nbuk && hist[t] > 0) atomicAdd(&bcnt[t], hist[t]);
}

// 1-block exclusive scan over bucket counts -> gbase (bases) and gbcur (cursors).
__global__ void bscan_kernel(const int* __restrict__ bcnt, int* __restrict__ gbase,
                             int* __restrict__ gbcur, int nbuk, int E) {
  __shared__ int sdata[BLK];
  int t = threadIdx.x;
  int v = (t < nbuk) ? bcnt[t] : 0;
  sdata[t] = v;
  __syncthreads();
  for (int off = 1; off < BLK; off <<= 1) {
    int x = (t >= off) ? sdata[t - off] : 0;
    __syncthreads();
    sdata[t] += x;
    __syncthreads();
  }
  int excl = sdata[t] - v;
  if (t < nbuk) { gbase[t] = excl; gbcur[t] = excl; }
  if (t == 0) gbase[nbuk] = E;
}

// Pass 1: LDS-binned scatter. Each tile reserves ONE contiguous chunk per bucket
// (single global atomicAdd) and writes each bucket's edges as a contiguous burst.
__global__ void scatter_pairs_lds_kernel(const int* __restrict__ src, const int* __restrict__ dst,
                                         int* __restrict__ gbcur, int2* __restrict__ pairs,
                                         int E, int nbuk) {
  __shared__ int hist[256];
  __shared__ int chunk[256];
  int t = threadIdx.x;
  hist[t] = 0;
  __syncthreads();
  int base = blockIdx.x * TILE;
  int es[EPT], ed[EPT];
#pragma unroll
  for (int k = 0; k < EPT; k++) {
    int e = base + k * BLK + t;
    if (e < E) {
      es[k] = src[e];
      ed[k] = dst[e];
      atomicAdd(&hist[ed[k] >> BSHIFT], 1);
    } else {
      ed[k] = -1;
    }
  }
  __syncthreads();
  if (t < nbuk && hist[t] > 0) chunk[t] = atomicAdd(&gbcur[t], hist[t]);
  __syncthreads();
#pragma unroll
  for (int k = 0; k < EPT; k++) {
    if (ed[k] >= 0) {
      int p = atomicAdd(&chunk[ed[k] >> BSHIFT], 1);
      pairs[p] = make_int2(es[k], ed[k]);
    }
  }
}

// Pass 2: one block per bucket. Per-node counts + exclusive scan entirely in LDS,
// writes row_start slice, then scatters csr within its own ~32KB region.
__global__ void bucket_build_kernel(const int2* __restrict__ pairs, const int* __restrict__ gbase,
                                    int* __restrict__ row_start, int* __restrict__ csr,
                                    int n, int nbuk, int E) {
  __shared__ int cnt[512];
  __shared__ int excl[512];
  __shared__ int s2[BLK];
  int b = blockIdx.x;
  int t = threadIdx.x;
  int n0 = b << BSHIFT;
  int n1 = min(n0 + (1 << BSHIFT), n);
  int bb0 = gbase[b], bb1 = gbase[b + 1];
  cnt[t] = 0; cnt[t + 256] = 0;
  __syncthreads();
  for (int r = bb0 + t; r < bb1; r += BLK) atomicAdd(&cnt[pairs[r].y - n0], 1);
  __syncthreads();
  // pairwise sums then 256-wide scan
  s2[t] = cnt[2 * t] + cnt[2 * t + 1];
  __syncthreads();
  int v = s2[t];
  for (int off = 1; off < BLK; off <<= 1) {
    int x = (t >= off) ? s2[t - off] : 0;
    __syncthreads();
    s2[t] += x;
    __syncthreads();
  }
  int e2 = s2[t] - v;  // exclusive over pair-sums
  excl[2 * t] = e2;
  excl[2 * t + 1] = e2 + cnt[2 * t];
  __syncthreads();
  // row_start for this bucket's nodes
  for (int k = t; k < n1 - n0; k += BLK) row_start[n0 + k] = bb0 + excl[k];
  if (b == nbuk - 1 && t == 0) row_start[n] = E;
  // reuse cnt[] as global-position cursors
  cnt[2 * t] = bb0 + excl[2 * t];
  cnt[2 * t + 1] = bb0 + excl[2 * t + 1];
  __syncthreads();
  for (int r = bb0 + t; r < bb1; r += BLK) {
    int2 pr = pairs[r];
    int pos = atomicAdd(&cnt[pr.y - n0], 1);
    csr[pos] = pr.x;
  }
}

// ---------------- FeaSt heads=4 ----------------

// xu[i,h] = sum_k x[i,k] * u[k,h]   (u is 16x4 row-major)
__global__ void xu4_kernel(const float* __restrict__ x, const float* __restrict__ u,
                           float* __restrict__ xu, int n) {
  __shared__ float su[64];
  if (threadIdx.x < 64) su[threadIdx.x] = u[threadIdx.x];
  __syncthreads();
  int i = blockIdx.x * blockDim.x + threadIdx.x;
  if (i >= n) return;
  const float4* xi = (const float4*)(x + i * 16);
  float a0 = 0.f, a1 = 0.f, a2 = 0.f, a3 = 0.f;
#pragma unroll
  for (int g = 0; g < 4; g++) {
    float4 v = xi[g];
    a0 += v.x * su[(g*4+0)*4+0] + v.y * su[(g*4+1)*4+0] + v.z * su[(g*4+2)*4+0] + v.w * su[(g*4+3)*4+0];
    a1 += v.x * su[(g*4+0)*4+1] + v.y * su[(g*4+1)*4+1] + v.z * su[(g*4+2)*4+1] + v.w * su[(g*4+3)*4+1];
    a2 += v.x * su[(g*4+0)*4+2] + v.y * su[(g*4+1)*4+2] + v.z * su[(g*4+2)*4+2] + v.w * su[(g*4+3)*4+2];
    a3 += v.x * su[(g*4+0)*4+3] + v.y * su[(g*4+1)*4+3] + v.z * su[(g*4+2)*4+3] + v.w * su[(g*4+3)*4+3];
  }
  *(float4*)(xu + i * 4) = make_float4(a0, a1, a2, a3);
}

// 4 threads per node. sub = tid&3 handles neighbors r0+sub, r0+sub+4, ...
// acc quad-reduced via shfl_xor; each sub-lane emits output float4 #sub.
// EPI: 0 = relu->out ; 1 = raw->out ; 2 = raw->out2 AND relu->out
template <int EPI>
__global__ void gather4_kernel(const float* __restrict__ x, const float* __restrict__ xu,
                               const int* __restrict__ row_start, const int* __restrict__ csr,
                               const float* __restrict__ W, const float* __restrict__ c,
                               const float* __restrict__ b,
                               float* __restrict__ out, float* __restrict__ out2, int n) {
  __shared__ float4 sW[256];  // W: 16 x 64 row-major; float4 idx = k*16 + h*4 + og
  __shared__ float sc[4];
  __shared__ float sb[16];
  {
    int t = threadIdx.x;
    for (int k = t; k < 1024; k += blockDim.x) ((float*)sW)[k] = W[k];
    if (t < 4) sc[t] = c[t];
    if (t < 16) sb[t] = b[t];
  }
  __syncthreads();
  int tid = blockIdx.x * blockDim.x + threadIdx.x;
  int i = tid >> 2;
  int sub = tid & 3;
  if (i >= n) return;

  float4 xui = *(const float4*)(xu + i * 4);
  float acc[4][16];
#pragma unroll
  for (int h = 0; h < 4; h++)
#pragma unroll
    for (int k = 0; k < 16; k++) acc[h][k] = 0.f;

  // self loop: logits = c  ->  q = softmax(c). Assigned to sub 3 (lightest tail).
  if (sub == 3) {
    float m = fmaxf(fmaxf(sc[0], sc[1]), fmaxf(sc[2], sc[3]));
    float e0 = __expf(sc[0] - m), e1 = __expf(sc[1] - m), e2 = __expf(sc[2] - m), e3 = __expf(sc[3] - m);
    float inv = 1.0f / (e0 + e1 + e2 + e3);
    float q[4] = {e0 * inv, e1 * inv, e2 * inv, e3 * inv};
    const float4* xi = (const float4*)(x + i * 16);
#pragma unroll
    for (int g = 0; g < 4; g++) {
      float4 v = xi[g];
#pragma unroll
      for (int h = 0; h < 4; h++) {
        acc[h][g * 4 + 0] += q[h] * v.x;
        acc[h][g * 4 + 1] += q[h] * v.y;
        acc[h][g * 4 + 2] += q[h] * v.z;
        acc[h][g * 4 + 3] += q[h] * v.w;
      }
    }
  }

  int r0 = row_start[i], r1 = row_start[i + 1];
  for (int r = r0 + sub; r < r1; r += 4) {
    int j = csr[r];
    float4 xuj = *(const float4*)(xu + j * 4);
    float l0 = xuj.x - xui.x + sc[0];
    float l1 = xuj.y - xui.y + sc[1];
    float l2 = xuj.z - xui.z + sc[2];
    float l3 = xuj.w - xui.w + sc[3];
    float m = fmaxf(fmaxf(l0, l1), fmaxf(l2, l3));
    float e0 = __expf(l0 - m), e1 = __expf(l1 - m), e2 = __expf(l2 - m), e3 = __expf(l3 - m);
    float inv = 1.0f / (e0 + e1 + e2 + e3);
    float q0 = e0 * inv, q1 = e1 * inv, q2 = e2 * inv, q3 = e3 * inv;
    const float4* xj = (const float4*)(x + j * 16);
#pragma unroll
    for (int g = 0; g < 4; g++) {
      float4 v = xj[g];
      acc[0][g * 4 + 0] += q0 * v.x; acc[0][g * 4 + 1] += q0 * v.y; acc[0][g * 4 + 2] += q0 * v.z; acc[0][g * 4 + 3] += q0 * v.w;
      acc[1][g * 4 + 0] += q1 * v.x; acc[1][g * 4 + 1] += q1 * v.y; acc[1][g * 4 + 2] += q1 * v.z; acc[1][g * 4 + 3] += q1 * v.w;
      acc[2][g * 4 + 0] += q2 * v.x; acc[2][g * 4 + 1] += q2 * v.y; acc[2][g * 4 + 2] += q2 * v.z; acc[2][g * 4 + 3] += q2 * v.w;
      acc[3][g * 4 + 0] += q3 * v.x; acc[3][g * 4 + 1] += q3 * v.y; acc[3][g * 4 + 2] += q3 * v.z; acc[3][g * 4 + 3] += q3 * v.w;
    }
  }

  // quad reduction (lanes {4m,4m+1,4m+2,4m+3} hold partials of node i)
#pragma unroll
  for (int h = 0; h < 4; h++)
#pragma unroll
    for (int k = 0; k < 16; k++) {
      float v = acc[h][k];
      v += __shfl_xor(v, 1);
      v += __shfl_xor(v, 2);
      acc[h][k] = v;
    }

  float invdeg = 1.0f / (float)(r1 - r0 + 1);
  // each sub-lane computes output float4 #sub
  {
    int og = sub;
    float s0 = 0.f, s1 = 0.f, s2 = 0.f, s3 = 0.f;
#pragma unroll
    for (int k = 0; k < 16; k++) {
#pragma unroll
      for (int h = 0; h < 4; h++) {
        float4 w = sW[k * 16 + h * 4 + og];
        float a = acc[h][k];
        s0 += a * w.x; s1 += a * w.y; s2 += a * w.z; s3 += a * w.w;
      }
    }
    float o0 = s0 * invdeg + sb[og * 4 + 0];
    float o1 = s1 * invdeg + sb[og * 4 + 1];
    float o2 = s2 * invdeg + sb[og * 4 + 2];
    float o3 = s3 * invdeg + sb[og * 4 + 3];
    if (EPI == 1) {
      *(float4*)(out + i * 16 + og * 4) = make_float4(o0, o1, o2, o3);
    } else if (EPI == 0) {
      *(float4*)(out + i * 16 + og * 4) =
          make_float4(fmaxf(o0, 0.f), fmaxf(o1, 0.f), fmaxf(o2, 0.f), fmaxf(o3, 0.f));
    } else {
      *(float4*)(out2 + i * 16 + og * 4) = make_float4(o0, o1, o2, o3);
      *(float4*)(out + i * 16 + og * 4) =
          make_float4(fmaxf(o0, 0.f), fmaxf(o1, 0.f), fmaxf(o2, 0.f), fmaxf(o3, 0.f));
    }
  }
}

// ---------------- FeaSt heads=1 (softmax over 1 head == 1: pure mean agg + matvec) ----------------
// 4 threads per node, same decomposition as gather4.

template <int RELU>
__global__ void gather1_kernel(const float* __restrict__ x, const int* __restrict__ row_start,
                               const int* __restrict__ csr, const float* __restrict__ W,
                               const float* __restrict__ b, float* __restrict__ out, int n) {
  __shared__ float4 sW[64];  // 16x16, float4 idx = k*4+og
  __shared__ float sb[16];
  {
    int t = threadIdx.x;
    for (int k = t; k < 256; k += blockDim.x) ((float*)sW)[k] = W[k];
    if (t < 16) sb[t] = b[t];
  }
  __syncthreads();
  int tid = blockIdx.x * blockDim.x + threadIdx.x;
  int i = tid >> 2;
  int sub = tid & 3;
  if (i >= n) return;

  float acc[16];
#pragma unroll
  for (int k = 0; k < 16; k++) acc[k] = 0.f;

  if (sub == 3) {  // self loop
    const float4* xi = (const float4*)(x + i * 16);
#pragma unroll
    for (int g = 0; g < 4; g++) {
      float4 v = xi[g];
      acc[g * 4 + 0] += v.x; acc[g * 4 + 1] += v.y; acc[g * 4 + 2] += v.z; acc[g * 4 + 3] += v.w;
    }
  }

  int r0 = row_start[i], r1 = row_start[i + 1];
  for (int r = r0 + sub; r < r1; r += 4) {
    int j = csr[r];
    const float4* xj = (const float4*)(x + j * 16);
#pragma unroll
    for (int g = 0; g < 4; g++) {
      float4 v = xj[g];
      acc[g * 4 + 0] += v.x; acc[g * 4 + 1] += v.y; acc[g * 4 + 2] += v.z; acc[g * 4 + 3] += v.w;
    }
  }

#pragma unroll
  for (int k = 0; k < 16; k++) {
    float v = acc[k];
    v += __shfl_xor(v, 1);
    v += __shfl_xor(v, 2);
    acc[k] = v;
  }

  float invdeg = 1.0f / (float)(r1 - r0 + 1);
  {
    int og = sub;
    float s0 = 0.f, s1 = 0.f, s2 = 0.f, s3 = 0.f;
#pragma unroll
    for (int k = 0; k < 16; k++) {
      float4 w = sW[k * 4 + og];
      float a = acc[k];
      s0 += a * w.x; s1 += a * w.y; s2 += a * w.z; s3 += a * w.w;
    }
    float o0 = s0 * invdeg + sb[og * 4 + 0];
    float o1 = s1 * invdeg + sb[og * 4 + 1];
    float o2 = s2 * invdeg + sb[og * 4 + 2];
    float o3 = s3 * invdeg + sb[og * 4 + 3];
    if (RELU) {
      o0 = fmaxf(o0, 0.f); o1 = fmaxf(o1, 0.f); o2 = fmaxf(o2, 0.f); o3 = fmaxf(o3, 0.f);
    }
    *(float4*)(out + i * 16 + og * 4) = make_float4(o0, o1, o2, o3);
  }
}

// ---------------- BatchNorm ----------------

// Per-thread ls/lq, 64-lane shuffle butterfly, one global atomicAdd per value per
// block. (Previous version did 256-thread same-address LDS atomicAdds: 8192
// serialized RMWs ~= 64us — the whole kernel cost was the atomic tail.)
__global__ void bn_stats_kernel(const float* __restrict__ x, float* __restrict__ stats, int n) {
  __shared__ float wbuf[4][32];
  int t = threadIdx.x;
  float ls[16], lq[16];
#pragma unroll
  for (int k = 0; k < 16; k++) { ls[k] = 0.f; lq[k] = 0.f; }
  for (int i = blockIdx.x * blockDim.x + t; i < n; i += gridDim.x * blockDim.x) {
    const float4* xi = (const float4*)(x + i * 16);
#pragma unroll
    for (int g = 0; g < 4; g++) {
      float4 v = xi[g];
      ls[g * 4 + 0] += v.x; lq[g * 4 + 0] += v.x * v.x;
      ls[g * 4 + 1] += v.y; lq[g * 4 + 1] += v.y * v.y;
      ls[g * 4 + 2] += v.z; lq[g * 4 + 2] += v.z * v.z;
      ls[g * 4 + 3] += v.w; lq[g * 4 + 3] += v.w * v.w;
    }
  }
  // 64-lane butterfly: all lanes end with the wave sum
#pragma unroll
  for (int k = 0; k < 16; k++) {
    for (int off = 1; off < 64; off <<= 1) {
      ls[k] += __shfl_xor(ls[k], off);
      lq[k] += __shfl_xor(lq[k], off);
    }
  }
  int wid = t >> 6, lane = t & 63;
  if (lane < 16) wbuf[wid][lane] = ls[lane];          // lane k stores channel k
  if (lane >= 16 && lane < 32) wbuf[wid][lane] = lq[lane - 16];
  __syncthreads();
  if (t < 32) {
    float s = wbuf[0][t] + wbuf[1][t] + wbuf[2][t] + wbuf[3][t];
    atomicAdd(&stats[t], s);
  }
}

// RESID: out = relu(bn(x)) (+ r1 + r2 if RESID)
template <int RESID>
__global__ void bn_apply_kernel(const float* __restrict__ x, const float* __restrict__ stats,
                                const float* __restrict__ g, const float* __restrict__ be,
                                const float* __restrict__ r1, const float* __restrict__ r2,
                                float* __restrict__ out, int n) {
  __shared__ float sscale[16], sshift[16];
  int t = threadIdx.x;
  if (t < 16) {
    float invn = 1.0f / (float)n;
    float mu = stats[t] * invn;
    float var = stats[16 + t] * invn - mu * mu;
    float sc = g[t] * rsqrtf(var + 1e-5f);
    sscale[t] = sc;
    sshift[t] = be[t] - mu * sc;
  }
  __syncthreads();
  int i = blockIdx.x * blockDim.x + t;
  if (i >= n) return;
#pragma unroll
  for (int og = 0; og < 4; og++) {
    float4 v = *(const float4*)(x + i * 16 + og * 4);
    float o0 = fmaxf(v.x * sscale[og * 4 + 0] + sshift[og * 4 + 0], 0.f);
    float o1 = fmaxf(v.y * sscale[og * 4 + 1] + sshift[og * 4 + 1], 0.f);
    float o2 = fmaxf(v.z * sscale[og * 4 + 2] + sshift[og * 4 + 2], 0.f);
    float o3 = fmaxf(v.w * sscale[og * 4 + 3] + sshift[og * 4 + 3], 0.f);
    if (RESID) {
      float4 a = *(const float4*)(r1 + i * 16 + og * 4);
      float4 bb = *(const float4*)(r2 + i * 16 + og * 4);
      o0 += a.x + bb.x; o1 += a.y + bb.y; o2 += a.z + bb.z; o3 += a.w + bb.w;
    }
    *(float4*)(out + i * 16 + og * 4) = make_float4(o0, o1, o2, o3);
  }
}

// ---------------- MLP head: 16 ->64 relu ->64 relu ->16 relu ->1 sigmoid ----------------
// 4 threads per node; lane sub owns activations [sub*16, sub*16+16) of each 64-wide
// layer (16 VGPRs, no spill). Cross-lane operands via width-4 shfl.

__global__ void mlp_kernel(const float* __restrict__ h,
                           const float* __restrict__ lw1, const float* __restrict__ lb1,
                           const float* __restrict__ lw2, const float* __restrict__ lb2,
                           const float* __restrict__ lw3, const float* __restrict__ lb3,
                           const float* __restrict__ ow, const float* __restrict__ ob,
                           float* __restrict__ out, int n) {
  __shared__ float4 s1[256];   // 16x64, float4 idx = k*16 + og
  __shared__ float4 s2[1024];  // 64x64, float4 idx = k*16 + og
  __shared__ float4 s3[256];   // 64x16, float4 idx = k*4 + og
  __shared__ float sb1[64], sb2[64], sb3[16], sow[16], sob[1];
  {
    int t = threadIdx.x;
    for (int k = t; k < 1024; k += blockDim.x) ((float*)s1)[k] = lw1[k];
    for (int k = t; k < 4096; k += blockDim.x) ((float*)s2)[k] = lw2[k];
    for (int k = t; k < 1024; k += blockDim.x) ((float*)s3)[k] = lw3[k];
    if (t < 64) sb1[t] = lb1[t];
    if (t < 64) sb2[t] = lb2[t];
    if (t < 16) sb3[t] = lb3[t];
    if (t < 16) sow[t] = ow[t];
    if (t == 0) sob[0] = ob[0];
  }
  __syncthreads();
  int tid = blockIdx.x * blockDim.x + threadIdx.x;
  int i = tid >> 2;
  int sub = tid & 3;
  if (i >= n) return;

  // each lane loads its quarter of the input (wave covers 16 nodes x 64B contiguous)
  float4 inq = *(const float4*)(h + i * 16 + sub * 4);
  float in4[4] = {inq.x, inq.y, inq.z, inq.w};

  // ---- L1: 16 -> 64, lane sub computes outputs [sub*16, sub*16+16) ----
  float a[16];
#pragma unroll
  for (int g = 0; g < 4; g++) {
    int og = sub * 4 + g;
    a[g * 4 + 0] = sb1[og * 4 + 0]; a[g * 4 + 1] = sb1[og * 4 + 1];
    a[g * 4 + 2] = sb1[og * 4 + 2]; a[g * 4 + 3] = sb1[og * 4 + 3];
  }
#pragma unroll
  for (int k = 0; k < 16; k++) {
    float v = __shfl(in4[k & 3], k >> 2, 4);
#pragma unroll
    for (int g = 0; g < 4; g++) {
      float4 w = s1[k * 16 + sub * 4 + g];
      a[g * 4 + 0] += v * w.x; a[g * 4 + 1] += v * w.y;
      a[g * 4 + 2] += v * w.z; a[g * 4 + 3] += v * w.w;
    }
  }
#pragma unroll
  for (int k = 0; k < 16; k++) a[k] = fmaxf(a[k], 0.f);

  // ---- L2: 64 -> 64, lane sub computes outputs [sub*16, sub*16+16) ----
  float b2[16];
#pragma unroll
  for (int g = 0; g < 4; g++) {
    int og = sub * 4 + g;
    b2[g * 4 + 0] = sb2[og * 4 + 0]; b2[g * 4 + 1] = sb2[og * 4 + 1];
    b2[g * 4 + 2] = sb2[og * 4 + 2]; b2[g * 4 + 3] = sb2[og * 4 + 3];
  }
#pragma unroll
  for (int k = 0; k < 64; k++) {
    float v = __shfl(a[k & 15], k >> 4, 4);
#pragma unroll
    for (int g = 0; g < 4; g++) {
      float4 w = s2[k * 16 + sub * 4 + g];
      b2[g * 4 + 0] += v * w.x; b2[g * 4 + 1] += v * w.y;
      b2[g * 4 + 2] += v * w.z; b2[g * 4 + 3] += v * w.w;
    }
  }
#pragma unroll
  for (int k = 0; k < 16; k++) b2[k] = fmaxf(b2[k], 0.f);

  // ---- L3: 64 -> 16, lane sub computes outputs [sub*4, sub*4+4) ----
  float c0 = sb3[sub * 4 + 0], c1 = sb3[sub * 4 + 1], c2 = sb3[sub * 4 + 2], c3v = sb3[sub * 4 + 3];
#pragma unroll
  for (int k = 0; k < 64; k++) {
    float v = __shfl(b2[k & 15], k >> 4, 4);
    float4 w = s3[k * 4 + sub];
    c0 += v * w.x; c1 += v * w.y; c2 += v * w.z; c3v += v * w.w;
  }
  c0 = fmaxf(c0, 0.f); c1 = fmaxf(c1, 0.f); c2 = fmaxf(c2, 0.f); c3v = fmaxf(c3v, 0.f);

  // ---- out: 16 -> 1 sigmoid (quad reduce) ----
  float zp = c0 * sow[sub * 4 + 0] + c1 * sow[sub * 4 + 1] +
             c2 * sow[sub * 4 + 2] + c3v * sow[sub * 4 + 3];
  zp += __shfl_xor(zp, 1);
  zp += __shfl_xor(zp, 2);
  if (sub == 0) out[i] = 1.0f / (1.0f + __expf(-(zp + sob[0])));
}

// ---------------- launch ----------------

extern "C" void kernel_launch(void* const* d_in, const int* in_sizes, int n_in,
                              void* d_out, int out_size, void* d_ws, size_t ws_size,
                              hipStream_t stream) {
  const float* x = (const float*)d_in[0];
  const int* ei = (const int*)d_in[1];
  const int N = in_sizes[0] / 16;
  const int E = in_sizes[1] / 2;
  const int* srcp = ei;
  const int* dstp = ei + E;

  const float* W1 = (const float*)d_in[2];  const float* u1 = (const float*)d_in[3];
  const float* c1 = (const float*)d_in[4];  const float* b1 = (const float*)d_in[5];
  const float* W2 = (const float*)d_in[6];  const float* u2 = (const float*)d_in[7];
  const float* c2 = (const float*)d_in[8];  const float* b2 = (const float*)d_in[9];
  const float* W3 = (const float*)d_in[10]; const float* u3 = (const float*)d_in[11];
  const float* c3 = (const float*)d_in[12]; const float* b3 = (const float*)d_in[13];
  const float* W4 = (const float*)d_in[14]; const float* b4 = (const float*)d_in[17];
  const float* W5 = (const float*)d_in[18]; const float* b5 = (const float*)d_in[21];
  const float* W6 = (const float*)d_in[22]; const float* b6 = (const float*)d_in[25];
  const float* g1 = (const float*)d_in[26]; const float* be1 = (const float*)d_in[27];
  const float* g2 = (const float*)d_in[28]; const float* be2 = (const float*)d_in[29];
  const float* lw1 = (const float*)d_in[30]; const float* lb1 = (const float*)d_in[31];
  const float* lw2 = (const float*)d_in[32]; const float* lb2 = (const float*)d_in[33];
  const float* lw3 = (const float*)d_in[34]; const float* lb3 = (const float*)d_in[35];
  const float* ow = (const float*)d_in[36]; const float* ob = (const float*)d_in[37];
  float* out = (float*)d_out;

  char* ws = (char*)d_ws;
  size_t off = 0;
  auto alloc = [&](size_t bytes) -> void* {
    void* p = ws + off;
    off = (off + bytes + 255) & ~(size_t)255;
    return p;
  };
  int* row_start = (int*)alloc((size_t)(N + 1) * 4);
  int* csr = (int*)alloc((size_t)E * 4);
  float* xu = (float*)alloc((size_t)N * 4 * 4);
  float* bufA = (float*)alloc((size_t)N * 16 * 4);
  float* bufB = (float*)alloc((size_t)N * 16 * 4);
  float* h2b = (float*)alloc((size_t)N * 16 * 4);
  float* h4b = (float*)alloc((size_t)N * 16 * 4);
  float* tmp = (float*)alloc((size_t)N * 16 * 4);
  float* stats = (float*)alloc(32 * 4);
  const int NBUK = (N + (1 << BSHIFT) - 1) >> BSHIFT;
  int* bcnt = (int*)alloc((size_t)NBUK * 4);
  int* gbase = (int*)alloc((size_t)(NBUK + 1) * 4);
  int* gbcur = (int*)alloc((size_t)NBUK * 4);
  // pairs staging (E * 8B = 12.8MB) aliases bufA+bufB, which are contiguous
  // (N*16*4 = 6.4MB each, 256B-aligned with no gap) and unused until layer 1.
  int2* pairs = (int2*)bufA;

  const int NB = (N + BLK - 1) / BLK;       // node-parallel grid (1 thread/node)
  const int NG = (4 * N + BLK - 1) / BLK;   // 4-threads-per-node grid
  const int NT = (E + TILE - 1) / TILE;     // edge tiles for binning kernels

  // ---- CSR build (per call; ws is re-poisoned every launch) ----
  hipMemsetAsync(bcnt, 0, (size_t)NBUK * 4, stream);
  bhist_kernel<<<NT, BLK, 0, stream>>>(dstp, bcnt, E, NBUK);
  bscan_kernel<<<1, BLK, 0, stream>>>(bcnt, gbase, gbcur, NBUK, E);
  scatter_pairs_lds_kernel<<<NT, BLK, 0, stream>>>(srcp, dstp, gbcur, pairs, E, NBUK);
  bucket_build_kernel<<<NBUK, BLK, 0, stream>>>(pairs, gbase, row_start, csr, N, NBUK, E);

  // ---- Layer 1: h = relu(feast4(x)) -> bufA ----
  xu4_kernel<<<NB, BLK, 0, stream>>>(x, u1, xu, N);
  gather4_kernel<0><<<NG, BLK, 0, stream>>>(x, xu, row_start, csr, W1, c1, b1, bufA, nullptr, N);

  // ---- Layer 2: h2 = feast4(bufA) (raw -> h2b), relu -> bufB ----
  xu4_kernel<<<NB, BLK, 0, stream>>>(bufA, u2, xu, N);
  gather4_kernel<2><<<NG, BLK, 0, stream>>>(bufA, xu, row_start, csr, W2, c2, b2, bufB, h2b, N);

  // ---- Layer 3: h3 = relu(bn(feast4(bufB))) -> bufA ----
  xu4_kernel<<<NB, BLK, 0, stream>>>(bufB, u3, xu, N);
  gather4_kernel<1><<<NG, BLK, 0, stream>>>(bufB, xu, row_start, csr, W3, c3, b3, tmp, nullptr, N);
  hipMemsetAsync(stats, 0, 32 * 4, stream);
  bn_stats_kernel<<<256, BLK, 0, stream>>>(tmp, stats, N);
  bn_apply_kernel<0><<<NB, BLK, 0, stream>>>(tmp, stats, g1, be1, nullptr, nullptr, bufA, N);

  // ---- Layer 4: h4 = relu(feast1(bufA)) -> h4b ----
  gather1_kernel<1><<<NG, BLK, 0, stream>>>(bufA, row_start, csr, W4, b4, h4b, N);

  // ---- Layer 5: h5 = relu(feast1(h4b)) -> bufB ----
  gather1_kernel<1><<<NG, BLK, 0, stream>>>(h4b, row_start, csr, W5, b5, bufB, N);

  // ---- Layer 6: h6 = relu(bn(feast1(bufB))) + h2b + h4b -> bufA ----
  gather1_kernel<0><<<NG, BLK, 0, stream>>>(bufB, row_start, csr, W6, b6, tmp, N);
  hipMemsetAsync(stats, 0, 32 * 4, stream);
  bn_stats_kernel<<<256, BLK, 0, stream>>>(tmp, stats, N);
  bn_apply_kernel<1><<<NB, BLK, 0, stream>>>(tmp, stats, g2, be2, h2b, h4b, bufA, N);

  // ---- MLP head -> out ----
  mlp_kernel<<<NG, BLK, 0, stream>>>(bufA, lw1, lb1, lw2, lb2, lw3, lb3, ow, ob, out, N);
}